// Round 5
// baseline (242.841 us; speedup 1.0000x reference)
//
#include <hip/hip_runtime.h>

typedef __bf16 bf16;
typedef __bf16 bf16x4 __attribute__((ext_vector_type(4)));
typedef __bf16 bf16x8 __attribute__((ext_vector_type(8)));
typedef float f32x4 __attribute__((ext_vector_type(4)));

#define LOG2E 1.44269504088896f

// async global->LDS, 16B per lane. LDS dest is wave-uniform base + lane*16
// (m104/m108): pass the lane-0 pointer; generic->AS(3) = low-32-bit truncation.
__device__ __forceinline__ void gl_lds16(const bf16* g, bf16* l) {
  __builtin_amdgcn_global_load_lds(
      reinterpret_cast<const __attribute__((address_space(1))) void*>((uintptr_t)g),
      reinterpret_cast<__attribute__((address_space(3))) void*>((uint32_t)(uintptr_t)l),
      16, 0, 0);
}

// ---------------- cast fp32 -> bf16 for weights + pm, and build RoPE cos/sin table ----------------
__global__ void cast3_kernel(const float* __restrict__ a, int na4, bf16* __restrict__ oa,
                             const float* __restrict__ b, int nb4, bf16* __restrict__ ob,
                             const float* __restrict__ c, int nc4, bf16* __restrict__ oc,
                             float2* __restrict__ tab, int nt) {
  int i = blockIdx.x * blockDim.x + threadIdx.x;
  if (i < na4 + nb4 + nc4) {
    const float* src; bf16* dst; int idx;
    if (i < na4)            { src = a; dst = oa; idx = i; }
    else if (i < na4 + nb4) { src = b; dst = ob; idx = i - na4; }
    else                    { src = c; dst = oc; idx = i - na4 - nb4; }
    float4 v = ((const float4*)src)[idx];
    bf16x4 o = { (bf16)v.x, (bf16)v.y, (bf16)v.z, (bf16)v.w };
    ((bf16x4*)dst)[idx] = o;
  } else {
    int idx = i - (na4 + nb4 + nc4);
    if (idx >= nt) return;
    int pos = idx >> 5, fi = idx & 31;
    float inv = exp2f((float)fi * -0.41524101186f);   // 10000^(-fi/32)
    float th = (float)pos * inv;
    float sn, cs;
    sincosf(th, &sn, &cs);
    tab[idx] = make_float2(cs, sn);
  }
}

// ---------------- RMSNorm: seq fp32 [8192][1024] -> x bf16 ----------------
__global__ __launch_bounds__(256) void rmsnorm_kernel(const float* __restrict__ seq,
                                                      const float* __restrict__ g,
                                                      bf16* __restrict__ xbf) {
  int row = blockIdx.x;
  int t = threadIdx.x;
  float4 x = ((const float4*)(seq + (size_t)row * 1024))[t];
  float ss = x.x*x.x + x.y*x.y + x.z*x.z + x.w*x.w;
  #pragma unroll
  for (int m = 32; m >= 1; m >>= 1) ss += __shfl_xor(ss, m, 64);
  __shared__ float red[4];
  if ((t & 63) == 0) red[t >> 6] = ss;
  __syncthreads();
  float tot = red[0] + red[1] + red[2] + red[3];
  float scale = rsqrtf(tot * (1.0f / 1024.0f) + 1.1920929e-07f);
  float4 gv = ((const float4*)g)[t];
  bf16x4 o = { (bf16)(x.x*scale*gv.x), (bf16)(x.y*scale*gv.y),
               (bf16)(x.z*scale*gv.z), (bf16)(x.w*scale*gv.w) };
  ((bf16x4*)(xbf + (size_t)row * 1024))[t] = o;
}

// ---------------- 128x256 4-wave pipelined GEMM, C[M,N] = A[M,K] * B[N,K]^T ----------------
// Round 5: 4 waves (256 threads), per-wave output 128x64 (acc[8][4]).  Rationale:
// the 8-wave version was LDS-read-bandwidth-bound (64 ds_read_b128/phase vs 515 cyc
// of MFMA/SIMD); halving the wave count cuts LDS reads to 48/phase while each SIMD's
// single wave still issues 32 MFMA/phase = 515 cyc of matrix-pipe work.  1 wave/SIMD
// -> __launch_bounds__(256,1) gives the 512-VGPR budget (acc 128 + frags 96 + addr).
// Perfect grid packing: (N/256)x(M/128) blocks (768 for QKV = 3 rounds, 256 = 1 round).
// Triple-buffered LDS (144 KiB), DMA 2 tiles ahead (12 gl_lds16/wave/tile), one counted
// vmcnt(12) per tile.  Register double-buffer: frag reads for phase p+1 issue BEFORE
// phase p's MFMA block.  Lifetimes (verified): buf (u+2)%3 holds tile u-1, last read
// tile u-1 phase 1, restaged top of tile u (2 barriers later); tile u+1's DMA drained
// by vmcnt(12)+barrier at end of tile u phase 1, read in tile u phase 2.
// Requires nt = K/64, nt % 3 == 1, nt >= 7 (K=1024 -> nt=16).
template<int OUTF>
__global__ __launch_bounds__(256, 1) void gemm128x256_kernel(const bf16* __restrict__ A,
                                                             const bf16* __restrict__ B,
                                                             void* __restrict__ C,
                                                             int M, int N, int K) {
  __shared__ bf16 As[3 * 8192];    // [buf][128 rows][64 k], XOR-swizzled chunks
  __shared__ bf16 Bs[3 * 16384];   // [buf][256 rows][64 k]
  int t = threadIdx.x;
  int lane = t & 63, wv = t >> 6;                // 4 waves
  int m16 = lane & 15, quad = lane >> 4;
  int wc = wv * 64;                              // per-wave C = 128 x 64
  int bn = blockIdx.x, bm = blockIdx.y;
  const bf16* Ab = A + (size_t)bm * 128 * K;
  const bf16* Bb = B + (size_t)bn * 256 * K;
  // per-lane pre-swizzled global source offsets: LDS chunk s (16B) of a tile holds
  // global k-chunk (s&7)^(row&7) of row s>>3 (row-major, 8 chunks of 8 bf16 per row).
  int aoff[4], boff[8];
  #pragma unroll
  for (int l = 0; l < 4; l++) { int s = l * 256 + t; int row = s >> 3; aoff[l] = row * K + ((s & 7) ^ (row & 7)) * 8; }
  #pragma unroll
  for (int l = 0; l < 8; l++) { int s = l * 256 + t; int row = s >> 3; boff[l] = row * K + ((s & 7) ^ (row & 7)) * 8; }
  f32x4 acc[8][4] = {};
  bf16x8 afA[8], bqA[4], afB[8], bqB[4];   // double-buffered frag registers

#define STGA(BUF, T) { int k0 = (T) * 64; \
    _Pragma("unroll") for (int l = 0; l < 4; l++) \
      gl_lds16(Ab + k0 + aoff[l], &As[(BUF) * 8192 + l * 2048 + wv * 512]); }
#define STGB(BUF, T) { int k0 = (T) * 64; \
    _Pragma("unroll") for (int l = 0; l < 8; l++) \
      gl_lds16(Bb + k0 + boff[l], &Bs[(BUF) * 16384 + l * 2048 + wv * 512]); }
#define DMA12(BUF, T) { STGA(BUF, T) STGB(BUF, T) }
#define VM12 asm volatile("s_waitcnt vmcnt(12)" ::: "memory");
#define VM0 asm volatile("s_waitcnt vmcnt(0)" ::: "memory");
#define BAR __builtin_amdgcn_s_barrier();
#define SB0 __builtin_amdgcn_sched_barrier(0);

#define RD(AF, BQ, BUF, KK) { \
    _Pragma("unroll") for (int i = 0; i < 8; i++) { \
      int row = i * 16 + m16; \
      AF[i] = *(const bf16x8*)(&As[(BUF) * 8192 + row * 64 + (((KK) * 4 + quad) ^ (row & 7)) * 8]); } \
    _Pragma("unroll") for (int j = 0; j < 4; j++) { \
      int row = wc + j * 16 + m16; \
      BQ[j] = *(const bf16x8*)(&Bs[(BUF) * 16384 + row * 64 + (((KK) * 4 + quad) ^ (row & 7)) * 8]); } }

#define MM(AF, BQ) { \
    _Pragma("unroll") for (int i = 0; i < 8; i++) { \
      _Pragma("unroll") for (int j = 0; j < 4; j++) { \
        acc[i][j] = __builtin_amdgcn_mfma_f32_16x16x32_bf16(AF[i], BQ[j], acc[i][j], 0, 0, 0); } } }

#define TILE_STEADY(CUR, NXT, DMAB, T) { \
    DMA12(DMAB, (T) + 2) \
    RD(afB, bqB, CUR, 1) SB0 \
    MM(afA, bqA) \
    VM12 BAR SB0 \
    RD(afA, bqA, NXT, 0) SB0 \
    MM(afB, bqB) \
    BAR SB0 }

  // prologue: stage tiles 0,1; publish tile 0 (vmcnt(12) leaves tile 1 in flight)
  DMA12(0, 0) DMA12(1, 1)
  VM12
  BAR SB0
  RD(afA, bqA, 0, 0) SB0

  int nt = K >> 6;                 // nt % 3 == 1, nt >= 7
  for (int tk = 0; tk < nt - 4; tk += 3) {
    TILE_STEADY(0, 1, 2, tk)
    TILE_STEADY(1, 2, 0, tk + 1)
    TILE_STEADY(2, 0, 1, tk + 2)
  }
  TILE_STEADY(0, 1, 2, nt - 4)     // stages tile nt-2 -> buf2
  TILE_STEADY(1, 2, 0, nt - 3)     // stages tile nt-1 -> buf0; vm12 publishes nt-2
  // tile nt-2 (cur=2, nxt=0): no DMA; drain tile nt-1 fully before its reads
  RD(afB, bqB, 2, 1) SB0
  MM(afA, bqA)
  VM0 BAR SB0
  RD(afA, bqA, 0, 0) SB0
  MM(afB, bqB)
  BAR SB0
  // tile nt-1 (cur=0): final tile, no staging, no barriers needed after
  RD(afB, bqB, 0, 1) SB0
  MM(afA, bqA)
  MM(afB, bqB)

#undef TILE_STEADY
#undef MM
#undef RD
#undef SB0
#undef BAR
#undef VM0
#undef VM12
#undef DMA12
#undef STGB
#undef STGA

  #pragma unroll
  for (int i = 0; i < 8; i++)
    #pragma unroll
    for (int j = 0; j < 4; j++)
      #pragma unroll
      for (int r = 0; r < 4; r++) {
        size_t row = (size_t)bm * 128 + i * 16 + quad * 4 + r;
        size_t col = (size_t)bn * 256 + wc + j * 16 + m16;
        float v = acc[i][j][r];
        if (OUTF) ((float*)C)[row * N + col] = v;
        else      ((bf16*)C)[row * N + col] = (bf16)v;
      }
}

// ---------------- attention: one block per (bw,h), 8 waves; RoPE fused; causal skip ----------------
// PV loop software-pipelined one chunk ahead using same-wave DS in-order execution
// (write(c+1) -> read(c+1) back-to-back, no lgkmcnt(0) drains; MFMA(c) runs on
// registers loaded last iteration while chunk c+1's DS traffic flows).  P k-group
// XOR-swizzled by quad (write banks all-distinct); V staging j XOR-swizzled by
// (d>>3)&3 for j<512 (staging writes 16-way -> 2-way conflict).  K tiles prefetched
// one ahead in QK^T.
__global__ __launch_bounds__(512) void attn_kernel(const bf16* __restrict__ qkv,
                                                   const bf16* __restrict__ pmbf,
                                                   const float2* __restrict__ tab,
                                                   bf16* __restrict__ ob) {
  __shared__ bf16 Ks[528 * 72];          // K rows (rope'd), padded stride 72
  __shared__ bf16 Vt[64 * 536 + 16];     // V transposed [d][j], stride 536, zero-padded tail
  __shared__ bf16 Pb[8 * 16 * 40];       // per-wave P staging, stride 40, quad-XOR swizzled
  int bh = blockIdx.x;
  int bw = bh >> 4, h = bh & 15;
  int seg = bw & 7;
  int t = threadIdx.x;
  int wv = t >> 6, lane = t & 63;
  int m16 = lane & 15, quad = lane >> 4;
  const bf16* qk_base = qkv + (size_t)bw * 512 * 3072 + h * 64;  // row s at +s*3072; K +1024; V +2048
  // stage K rows (pm rows 0..15 unroped, seq rows 16..527 roped at global pos)
  for (int ch = t; ch < 4224; ch += 512) {
    int row = ch >> 3, d0 = (ch & 7) * 8;
    bf16 tmp[8];
    if (row < 16) {
      *(uint4*)tmp = *(const uint4*)(pmbf + ((size_t)h * 16 + row) * 64 + d0);
    } else {
      int s = row - 16;
      *(uint4*)tmp = *(const uint4*)(qk_base + (size_t)s * 3072 + 1024 + d0);
      int pos = seg * 512 + s;
      const float2* tb = tab + pos * 32 + (d0 >> 1);
      #pragma unroll
      for (int p = 0; p < 4; p++) {
        float2 cs = tb[p];
        float x0 = (float)tmp[2 * p], x1 = (float)tmp[2 * p + 1];
        tmp[2 * p]     = (bf16)(x0 * cs.x - x1 * cs.y);
        tmp[2 * p + 1] = (bf16)(x1 * cs.x + x0 * cs.y);
      }
    }
    *(uint4*)(&Ks[row * 72 + d0]) = *(uint4*)tmp;
  }
  // stage V transposed (no rope); j<512 stored at column j ^ (((d>>3)&3)<<3)
  for (int ch = t; ch < 4224; ch += 512) {
    int row = ch >> 3, d0 = (ch & 7) * 8;
    bf16 tmp[8];
    if (row < 16) *(uint4*)tmp = *(const uint4*)(pmbf + ((size_t)(16 + h) * 16 + row) * 64 + d0);
    else          *(uint4*)tmp = *(const uint4*)(qk_base + (size_t)(row - 16) * 3072 + 2048 + d0);
    int rs = (row < 512) ? (row ^ ((ch & 3) << 3)) : row;   // g = ((d0+i)>>3)&3 = ch&3
    #pragma unroll
    for (int i = 0; i < 8; i++) Vt[(d0 + i) * 536 + rs] = tmp[i];
  }
  // zero-pad Vt cols 528..535 and the tail so ragged chunks read finite zeros
  if (t < 512) { int r = t >> 3, cc = 528 + (t & 7); Vt[r * 536 + cc] = (bf16)0.f; }
  if (t < 16) Vt[64 * 536 + t] = (bf16)0.f;
  __syncthreads();

  bf16* myP = &Pb[wv * 16 * 40];
  // per-lane constant offsets for the swizzled P buffer and Vt reads
  int prd = m16 * 40 + (((quad ^ (m16 >> 2)) & 3) << 3);               // P read (k-group=quad)
  int pw0 = ((((m16 >> 3) ^ quad) & 3) << 3) | (m16 & 7);              // P write col, half 0
  int pw1 = ((((2 | (m16 >> 3)) ^ quad) & 3) << 3) | (m16 & 7);        // P write col, half 1
  int vswz[4], vpl[4];
  #pragma unroll
  for (int dt = 0; dt < 4; dt++) {
    int d = dt * 16 + m16;
    vswz[dt] = d * 536 + (((quad ^ (d >> 3)) & 3) << 3);               // j<512 swizzled
    vpl[dt]  = d * 536 + (quad << 3);                                  // chunk 16 plain
  }
  for (int pass = 0; pass < 4; pass++) {
    int qi = (pass == 0) ? wv : (pass == 1) ? 15 - wv : (pass == 2) ? 16 + wv : 31 - wv;
    int q0 = qi * 16;
    int ntl = qi + 2;                       // visible score tiles: 0..qi+1
    int qrow = q0 + m16;
    int pos = seg * 512 + qrow;
    const bf16* qp = qk_base + (size_t)qrow * 3072;
    // load Q frags + rope + 1/8 scale in registers
    bf16 qr0[8], qr1[8];
    *(uint4*)qr0 = *(const uint4*)(qp + quad * 8);
    *(uint4*)qr1 = *(const uint4*)(qp + 32 + quad * 8);
    {
      const float2* tb0 = tab + pos * 32 + quad * 4;
      const float2* tb1 = tb0 + 16;
      #pragma unroll
      for (int p = 0; p < 4; p++) {
        float2 c0 = tb0[p], c1 = tb1[p];
        float a0 = (float)qr0[2 * p], a1 = (float)qr0[2 * p + 1];
        qr0[2 * p]     = (bf16)((a0 * c0.x - a1 * c0.y) * 0.125f);
        qr0[2 * p + 1] = (bf16)((a1 * c0.x + a0 * c0.y) * 0.125f);
        float b0 = (float)qr1[2 * p], b1 = (float)qr1[2 * p + 1];
        qr1[2 * p]     = (bf16)((b0 * c1.x - b1 * c1.y) * 0.125f);
        qr1[2 * p + 1] = (bf16)((b1 * c1.x + b0 * c1.y) * 0.125f);
      }
    }
    bf16x8 qf0 = *(bf16x8*)qr0;
    bf16x8 qf1 = *(bf16x8*)qr1;
    f32x4 s[34];                            // s[33] exists only as a never-taken select arm
    // QK^T with one-tile register prefetch (reads of tl+1 fly under MFMA of tl)
    bf16x8 kb0[2], kb1[2];
    kb0[0] = *(const bf16x8*)(&Ks[m16 * 72 + quad * 8]);
    kb1[0] = *(const bf16x8*)(&Ks[m16 * 72 + 32 + quad * 8]);
    #pragma unroll
    for (int tl = 0; tl < 33; tl++) {
      if (tl < ntl) {                       // wave-uniform guard
        if (tl + 1 < ntl) {
          kb0[(tl + 1) & 1] = *(const bf16x8*)(&Ks[((tl + 1) * 16 + m16) * 72 + quad * 8]);
          kb1[(tl + 1) & 1] = *(const bf16x8*)(&Ks[((tl + 1) * 16 + m16) * 72 + 32 + quad * 8]);
        }
        __builtin_amdgcn_sched_barrier(0);
        f32x4 acc = {0.f, 0.f, 0.f, 0.f};
        acc = __builtin_amdgcn_mfma_f32_16x16x32_bf16(qf0, kb0[tl & 1], acc, 0, 0, 0);
        acc = __builtin_amdgcn_mfma_f32_16x16x32_bf16(qf1, kb1[tl & 1], acc, 0, 0, 0);
        if (tl == qi + 1) {                 // diagonal tile: mask m16 > quad*4+r
          #pragma unroll
          for (int r = 0; r < 4; r++)
            if (m16 > quad * 4 + r) acc[r] = -1e30f;
        }
        s[tl] = acc;
      }
    }
    // softmax over visible tiles + 16 lanes of the column group
    float lrow[4];
    #pragma unroll
    for (int r = 0; r < 4; r++) {
      float mx = s[0][r];
      #pragma unroll
      for (int tl = 1; tl < 33; tl++) if (tl < ntl) mx = fmaxf(mx, s[tl][r]);
      mx = fmaxf(mx, __shfl_xor(mx, 1, 64));
      mx = fmaxf(mx, __shfl_xor(mx, 2, 64));
      mx = fmaxf(mx, __shfl_xor(mx, 4, 64));
      mx = fmaxf(mx, __shfl_xor(mx, 8, 64));
      float sum = 0.f;
      #pragma unroll
      for (int tl = 0; tl < 33; tl++) {
        if (tl < ntl) {
          float p = exp2f((s[tl][r] - mx) * LOG2E);
          s[tl][r] = p;
          sum += p;
        }
      }
      sum += __shfl_xor(sum, 1, 64);
      sum += __shfl_xor(sum, 2, 64);
      sum += __shfl_xor(sum, 4, 64);
      sum += __shfl_xor(sum, 8, 64);
      lrow[r] = sum;
    }
    // PV over visible chunks of 32 kv, pipelined one chunk ahead.
    // Same-wave DS ops execute in order: PWRITE(c+1) then PREAD(c+1) needs no drain,
    // and pf/vfr(c) were issued 13 DS ops ago -> MFMA(c) starts immediately.
    f32x4 o[4] = {};
    bf16x8 pf[2], vfr[2][4];

#define PWRITE(C) { \
      _Pragma("unroll") for (int half = 0; half < 2; half++) { \
        const int tl = 2 * (C) + half; \
        int pwo = half ? pw1 : pw0; \
        _Pragma("unroll") for (int r = 0; r < 4; r++) { \
          float pv = (tl < ntl) ? s[tl][r] : 0.f; \
          myP[(quad * 4 + r) * 40 + pwo] = (bf16)pv; } } }
#define PVLOAD(PAR, C) { \
      asm volatile("" ::: "memory"); \
      pf[PAR] = *(const bf16x8*)(&myP[prd]); \
      _Pragma("unroll") for (int dt = 0; dt < 4; dt++) \
        vfr[PAR][dt] = *(const bf16x8*)(&Vt[((C) < 16 ? vswz[dt] : vpl[dt]) + (C) * 32]); }

    PWRITE(0)
    PVLOAD(0, 0)
    #pragma unroll
    for (int c = 0; c < 17; c++) {
      if (2 * c < ntl) {                    // wave-uniform guard
        if (2 * (c + 1) < ntl) {            // prefetch chunk c+1
          PWRITE(c + 1)
          PVLOAD((c + 1) & 1, c + 1)
        }
        __builtin_amdgcn_sched_barrier(0);
        #pragma unroll
        for (int dt = 0; dt < 4; dt++)
          o[dt] = __builtin_amdgcn_mfma_f32_16x16x32_bf16(pf[c & 1], vfr[c & 1][dt], o[dt], 0, 0, 0);
      }
    }
#undef PVLOAD
#undef PWRITE
    // normalize + write to [8192][1024] merged layout
    float invl[4];
    #pragma unroll
    for (int r = 0; r < 4; r++) invl[r] = 1.0f / lrow[r];
    #pragma unroll
    for (int dt = 0; dt < 4; dt++)
      #pragma unroll
      for (int r = 0; r < 4; r++) {
        size_t row = (size_t)bw * 512 + q0 + quad * 4 + r;
        ob[row * 1024 + h * 64 + dt * 16 + m16] = (bf16)(o[dt][r] * invl[r]);
      }
  }
}

// ---------------- launch ----------------
extern "C" void kernel_launch(void* const* d_in, const int* in_sizes, int n_in,
                              void* d_out, int out_size, void* d_ws, size_t ws_size,
                              hipStream_t stream) {
  const float* seq  = (const float*)d_in[0];
  const float* g    = (const float*)d_in[1];
  const float* wqkv = (const float*)d_in[2];
  const float* wout = (const float*)d_in[3];
  const float* pm   = (const float*)d_in[4];
  float* out = (float*)d_out;
  char* ws = (char*)d_ws;
  bf16*   wqkv_bf = (bf16*)(ws);                  //  6,291,456
  bf16*   wout_bf = (bf16*)(ws + 6291456);        //  2,097,152
  bf16*   pm_bf   = (bf16*)(ws + 8388608);        //     65,536
  float2* tab     = (float2*)(ws + 8454144);      //  1,048,576 (4096 x 32 cos/sin)
  bf16*   x_bf    = (bf16*)(ws + 9502720);        // 16,777,216 (RMSNorm out, reused as attn out)
  bf16*   qkv_bf  = (bf16*)(ws + 26279936);       // 50,331,648 -> 76,611,584 total

  cast3_kernel<<<4640, 256, 0, stream>>>(wqkv, 786432, wqkv_bf,
                                         wout, 262144, wout_bf,
                                         pm, 8192, pm_bf,
                                         tab, 131072);
  rmsnorm_kernel<<<8192, 256, 0, stream>>>(seq, g, x_bf);
  gemm128x256_kernel<0><<<dim3(12, 64), 256, 0, stream>>>(x_bf, wqkv_bf, qkv_bf, 8192, 3072, 1024);
  attn_kernel<<<256, 512, 0, stream>>>(qkv_bf, pm_bf, tab, x_bf);
  gemm128x256_kernel<1><<<dim3(4, 64), 256, 0, stream>>>(x_bf, wout_bf, out, 8192, 1024, 1024);
}

// Round 6
// 238.065 us; speedup vs baseline: 1.0201x; 1.0201x over previous
//
#include <hip/hip_runtime.h>

typedef __bf16 bf16;
typedef __bf16 bf16x4 __attribute__((ext_vector_type(4)));
typedef __bf16 bf16x8 __attribute__((ext_vector_type(8)));
typedef float f32x4 __attribute__((ext_vector_type(4)));

#define LOG2E 1.44269504088896f

// async global->LDS, 16B per lane. LDS dest is wave-uniform base + lane*16
// (m104/m108): pass the lane-0 pointer; generic->AS(3) = low-32-bit truncation.
__device__ __forceinline__ void gl_lds16(const bf16* g, bf16* l) {
  __builtin_amdgcn_global_load_lds(
      reinterpret_cast<const __attribute__((address_space(1))) void*>((uintptr_t)g),
      reinterpret_cast<__attribute__((address_space(3))) void*>((uint32_t)(uintptr_t)l),
      16, 0, 0);
}

// ---------------- cast fp32 -> bf16 for weights + pm, and build RoPE cos/sin table ----------------
__global__ void cast3_kernel(const float* __restrict__ a, int na4, bf16* __restrict__ oa,
                             const float* __restrict__ b, int nb4, bf16* __restrict__ ob,
                             const float* __restrict__ c, int nc4, bf16* __restrict__ oc,
                             float2* __restrict__ tab, int nt) {
  int i = blockIdx.x * blockDim.x + threadIdx.x;
  if (i < na4 + nb4 + nc4) {
    const float* src; bf16* dst; int idx;
    if (i < na4)            { src = a; dst = oa; idx = i; }
    else if (i < na4 + nb4) { src = b; dst = ob; idx = i - na4; }
    else                    { src = c; dst = oc; idx = i - na4 - nb4; }
    float4 v = ((const float4*)src)[idx];
    bf16x4 o = { (bf16)v.x, (bf16)v.y, (bf16)v.z, (bf16)v.w };
    ((bf16x4*)dst)[idx] = o;
  } else {
    int idx = i - (na4 + nb4 + nc4);
    if (idx >= nt) return;
    int pos = idx >> 5, fi = idx & 31;
    float inv = exp2f((float)fi * -0.41524101186f);   // 10000^(-fi/32)
    float th = (float)pos * inv;
    float sn, cs;
    sincosf(th, &sn, &cs);
    tab[idx] = make_float2(cs, sn);
  }
}

// ---------------- RMSNorm: seq fp32 [8192][1024] -> x bf16 ----------------
__global__ __launch_bounds__(256) void rmsnorm_kernel(const float* __restrict__ seq,
                                                      const float* __restrict__ g,
                                                      bf16* __restrict__ xbf) {
  int row = blockIdx.x;
  int t = threadIdx.x;
  float4 x = ((const float4*)(seq + (size_t)row * 1024))[t];
  float ss = x.x*x.x + x.y*x.y + x.z*x.z + x.w*x.w;
  #pragma unroll
  for (int m = 32; m >= 1; m >>= 1) ss += __shfl_xor(ss, m, 64);
  __shared__ float red[4];
  if ((t & 63) == 0) red[t >> 6] = ss;
  __syncthreads();
  float tot = red[0] + red[1] + red[2] + red[3];
  float scale = rsqrtf(tot * (1.0f / 1024.0f) + 1.1920929e-07f);
  float4 gv = ((const float4*)g)[t];
  bf16x4 o = { (bf16)(x.x*scale*gv.x), (bf16)(x.y*scale*gv.y),
               (bf16)(x.z*scale*gv.z), (bf16)(x.w*scale*gv.w) };
  ((bf16x4*)(xbf + (size_t)row * 1024))[t] = o;
}

// ---------------- 128x256 8-wave pipelined GEMM, C[M,N] = A[M,K] * B[N,K]^T ----------------
// Round 6 = round 4 (best known: 59.5us QKV) + T5 setprio around MFMA blocks +
// hoisted per-lane ds_read addresses (kk1 addr = kk0 addr ^ 32 on the chunk bit)
// + DMA issue moved after the ds_read batch.  8 waves (512 thr), per-wave C 64x64,
// triple-buffered LDS (144 KiB), DMA 2 tiles ahead, counted vmcnt(6)/tile, register
// double-buffer (reads for phase p+1 issue before phase p's MFMA block).
// Requires nt = K/64, nt % 3 == 1, nt >= 7 (K=1024 -> nt=16).
template<int OUTF>
__global__ __launch_bounds__(512) void gemm128x256_kernel(const bf16* __restrict__ A,
                                                          const bf16* __restrict__ B,
                                                          void* __restrict__ C,
                                                          int M, int N, int K) {
  __shared__ bf16 As[3 * 8192];    // [buf][128 rows][64 k], XOR-swizzled chunks
  __shared__ bf16 Bs[3 * 16384];   // [buf][256 rows][64 k]
  int t = threadIdx.x;
  int lane = t & 63, wv = t >> 6;
  int m16 = lane & 15, quad = lane >> 4;
  int wr = (wv >> 2) * 64, wc = (wv & 3) * 64;   // 2M x 4N waves, per-wave C = 64x64
  int bn = blockIdx.x, bm = blockIdx.y;
  const bf16* Ab = A + (size_t)bm * 128 * K;
  const bf16* Bb = B + (size_t)bn * 256 * K;
  // per-lane pre-swizzled global source offsets: LDS chunk s (16B) of a tile holds
  // global k-chunk (s&7)^(row&7) of row s>>3 (row-major, 8 chunks of 8 bf16 per row).
  int aoff[2], boff[4];
  #pragma unroll
  for (int l = 0; l < 2; l++) { int s = l * 512 + t; int row = s >> 3; aoff[l] = row * K + ((s & 7) ^ (row & 7)) * 8; }
  #pragma unroll
  for (int l = 0; l < 4; l++) { int s = l * 512 + t; int row = s >> 3; boff[l] = row * K + ((s & 7) ^ (row & 7)) * 8; }
  // hoisted per-lane ds_read addresses (elements), kk=0; kk=1 is addr ^ 32
  int aadr[4], badr[4];
  #pragma unroll
  for (int i = 0; i < 4; i++) { int row = wr + i * 16 + m16; aadr[i] = row * 64 + ((quad ^ (row & 7)) * 8); }
  #pragma unroll
  for (int j = 0; j < 4; j++) { int row = wc + j * 16 + m16; badr[j] = row * 64 + ((quad ^ (row & 7)) * 8); }
  f32x4 acc[4][4] = {};
  bf16x8 afA[4], bqA[4], afB[4], bqB[4];   // double-buffered frag registers

#define STGA(BUF, T) { int k0 = (T) * 64; \
    gl_lds16(Ab + k0 + aoff[0], &As[(BUF) * 8192 + wv * 512]); \
    gl_lds16(Ab + k0 + aoff[1], &As[(BUF) * 8192 + 4096 + wv * 512]); }
#define STGB(BUF, T, L) { int k0 = (T) * 64; \
    gl_lds16(Bb + k0 + boff[L], &Bs[(BUF) * 16384 + (L) * 4096 + wv * 512]); }
#define DMA6(BUF, T) { STGA(BUF, T) STGB(BUF, T, 0) STGB(BUF, T, 1) STGB(BUF, T, 2) STGB(BUF, T, 3) }
#define VM6 asm volatile("s_waitcnt vmcnt(6)" ::: "memory");
#define VM0 asm volatile("s_waitcnt vmcnt(0)" ::: "memory");
#define BAR __builtin_amdgcn_s_barrier();
#define SB0 __builtin_amdgcn_sched_barrier(0);
#define PRIO1 __builtin_amdgcn_s_setprio(1);
#define PRIO0 __builtin_amdgcn_s_setprio(0);

#define RD(AF, BQ, BUF, KX) { \
    _Pragma("unroll") for (int i = 0; i < 4; i++) \
      AF[i] = *(const bf16x8*)(&As[(BUF) * 8192 + (aadr[i] ^ (KX))]); \
    _Pragma("unroll") for (int j = 0; j < 4; j++) \
      BQ[j] = *(const bf16x8*)(&Bs[(BUF) * 16384 + (badr[j] ^ (KX))]); }

#define MM(AF, BQ) { \
    _Pragma("unroll") for (int i = 0; i < 4; i++) { \
      _Pragma("unroll") for (int j = 0; j < 4; j++) { \
        acc[i][j] = __builtin_amdgcn_mfma_f32_16x16x32_bf16(AF[i], BQ[j], acc[i][j], 0, 0, 0); } } }

#define TILE_STEADY(CUR, NXT, DMAB, T) { \
    RD(afB, bqB, CUR, 32) SB0 \
    DMA6(DMAB, (T) + 2) SB0 \
    PRIO1 MM(afA, bqA) PRIO0 \
    VM6 BAR SB0 \
    RD(afA, bqA, NXT, 0) SB0 \
    PRIO1 MM(afB, bqB) PRIO0 \
    BAR SB0 }

  // prologue: stage tiles 0,1; publish tile 0 (vmcnt(6) leaves tile 1 in flight)
  DMA6(0, 0) DMA6(1, 1)
  VM6
  BAR SB0
  RD(afA, bqA, 0, 0) SB0

  int nt = K >> 6;                 // nt % 3 == 1, nt >= 7
  for (int tk = 0; tk < nt - 4; tk += 3) {
    TILE_STEADY(0, 1, 2, tk)
    TILE_STEADY(1, 2, 0, tk + 1)
    TILE_STEADY(2, 0, 1, tk + 2)
  }
  TILE_STEADY(0, 1, 2, nt - 4)     // stages tile nt-2 -> buf2
  TILE_STEADY(1, 2, 0, nt - 3)     // stages tile nt-1 -> buf0; vm6 publishes nt-2
  // tile nt-2 (cur=2, nxt=0): no DMA; drain tile nt-1 fully before its reads
  RD(afB, bqB, 2, 32) SB0
  PRIO1 MM(afA, bqA) PRIO0
  VM0 BAR SB0
  RD(afA, bqA, 0, 0) SB0
  PRIO1 MM(afB, bqB) PRIO0
  BAR SB0
  // tile nt-1 (cur=0): final tile, no staging, no barriers needed after
  RD(afB, bqB, 0, 32) SB0
  PRIO1 MM(afA, bqA)
  MM(afB, bqB) PRIO0

#undef TILE_STEADY
#undef MM
#undef RD
#undef PRIO1
#undef PRIO0
#undef SB0
#undef BAR
#undef VM0
#undef VM6
#undef DMA6
#undef STGB
#undef STGA

  #pragma unroll
  for (int i = 0; i < 4; i++)
    #pragma unroll
    for (int j = 0; j < 4; j++)
      #pragma unroll
      for (int r = 0; r < 4; r++) {
        size_t row = (size_t)bm * 128 + wr + i * 16 + quad * 4 + r;
        size_t col = (size_t)bn * 256 + wc + j * 16 + m16;
        float v = acc[i][j][r];
        if (OUTF) ((float*)C)[row * N + col] = v;
        else      ((bf16*)C)[row * N + col] = (bf16)v;
      }
}

// ---------------- attention: one block per (bw,h), 8 waves; RoPE fused; causal skip ----------------
// PV loop software-pipelined one chunk ahead using same-wave DS in-order execution
// (write(c+1) -> read(c+1) back-to-back, no lgkmcnt(0) drains; MFMA(c) runs on
// registers loaded last iteration while chunk c+1's DS traffic flows).  P k-group
// XOR-swizzled by quad (write banks all-distinct); V staging j XOR-swizzled by
// (d>>3)&3 for j<512 (staging writes 16-way -> 2-way conflict).  K tiles prefetched
// one ahead in QK^T.
__global__ __launch_bounds__(512) void attn_kernel(const bf16* __restrict__ qkv,
                                                   const bf16* __restrict__ pmbf,
                                                   const float2* __restrict__ tab,
                                                   bf16* __restrict__ ob) {
  __shared__ bf16 Ks[528 * 72];          // K rows (rope'd), padded stride 72
  __shared__ bf16 Vt[64 * 536 + 16];     // V transposed [d][j], stride 536, zero-padded tail
  __shared__ bf16 Pb[8 * 16 * 40];       // per-wave P staging, stride 40, quad-XOR swizzled
  int bh = blockIdx.x;
  int bw = bh >> 4, h = bh & 15;
  int seg = bw & 7;
  int t = threadIdx.x;
  int wv = t >> 6, lane = t & 63;
  int m16 = lane & 15, quad = lane >> 4;
  const bf16* qk_base = qkv + (size_t)bw * 512 * 3072 + h * 64;  // row s at +s*3072; K +1024; V +2048
  // stage K rows (pm rows 0..15 unroped, seq rows 16..527 roped at global pos)
  for (int ch = t; ch < 4224; ch += 512) {
    int row = ch >> 3, d0 = (ch & 7) * 8;
    bf16 tmp[8];
    if (row < 16) {
      *(uint4*)tmp = *(const uint4*)(pmbf + ((size_t)h * 16 + row) * 64 + d0);
    } else {
      int s = row - 16;
      *(uint4*)tmp = *(const uint4*)(qk_base + (size_t)s * 3072 + 1024 + d0);
      int pos = seg * 512 + s;
      const float2* tb = tab + pos * 32 + (d0 >> 1);
      #pragma unroll
      for (int p = 0; p < 4; p++) {
        float2 cs = tb[p];
        float x0 = (float)tmp[2 * p], x1 = (float)tmp[2 * p + 1];
        tmp[2 * p]     = (bf16)(x0 * cs.x - x1 * cs.y);
        tmp[2 * p + 1] = (bf16)(x1 * cs.x + x0 * cs.y);
      }
    }
    *(uint4*)(&Ks[row * 72 + d0]) = *(uint4*)tmp;
  }
  // stage V transposed (no rope); j<512 stored at column j ^ (((d>>3)&3)<<3)
  for (int ch = t; ch < 4224; ch += 512) {
    int row = ch >> 3, d0 = (ch & 7) * 8;
    bf16 tmp[8];
    if (row < 16) *(uint4*)tmp = *(const uint4*)(pmbf + ((size_t)(16 + h) * 16 + row) * 64 + d0);
    else          *(uint4*)tmp = *(const uint4*)(qk_base + (size_t)(row - 16) * 3072 + 2048 + d0);
    int rs = (row < 512) ? (row ^ ((ch & 3) << 3)) : row;   // g = ((d0+i)>>3)&3 = ch&3
    #pragma unroll
    for (int i = 0; i < 8; i++) Vt[(d0 + i) * 536 + rs] = tmp[i];
  }
  // zero-pad Vt cols 528..535 and the tail so ragged chunks read finite zeros
  if (t < 512) { int r = t >> 3, cc = 528 + (t & 7); Vt[r * 536 + cc] = (bf16)0.f; }
  if (t < 16) Vt[64 * 536 + t] = (bf16)0.f;
  __syncthreads();

  bf16* myP = &Pb[wv * 16 * 40];
  // per-lane constant offsets for the swizzled P buffer and Vt reads
  int prd = m16 * 40 + (((quad ^ (m16 >> 2)) & 3) << 3);               // P read (k-group=quad)
  int pw0 = ((((m16 >> 3) ^ quad) & 3) << 3) | (m16 & 7);              // P write col, half 0
  int pw1 = ((((2 | (m16 >> 3)) ^ quad) & 3) << 3) | (m16 & 7);        // P write col, half 1
  int vswz[4], vpl[4];
  #pragma unroll
  for (int dt = 0; dt < 4; dt++) {
    int d = dt * 16 + m16;
    vswz[dt] = d * 536 + (((quad ^ (d >> 3)) & 3) << 3);               // j<512 swizzled
    vpl[dt]  = d * 536 + (quad << 3);                                  // chunk 16 plain
  }
  for (int pass = 0; pass < 4; pass++) {
    int qi = (pass == 0) ? wv : (pass == 1) ? 15 - wv : (pass == 2) ? 16 + wv : 31 - wv;
    int q0 = qi * 16;
    int ntl = qi + 2;                       // visible score tiles: 0..qi+1
    int qrow = q0 + m16;
    int pos = seg * 512 + qrow;
    const bf16* qp = qk_base + (size_t)qrow * 3072;
    // load Q frags + rope + 1/8 scale in registers
    bf16 qr0[8], qr1[8];
    *(uint4*)qr0 = *(const uint4*)(qp + quad * 8);
    *(uint4*)qr1 = *(const uint4*)(qp + 32 + quad * 8);
    {
      const float2* tb0 = tab + pos * 32 + quad * 4;
      const float2* tb1 = tb0 + 16;
      #pragma unroll
      for (int p = 0; p < 4; p++) {
        float2 c0 = tb0[p], c1 = tb1[p];
        float a0 = (float)qr0[2 * p], a1 = (float)qr0[2 * p + 1];
        qr0[2 * p]     = (bf16)((a0 * c0.x - a1 * c0.y) * 0.125f);
        qr0[2 * p + 1] = (bf16)((a1 * c0.x + a0 * c0.y) * 0.125f);
        float b0 = (float)qr1[2 * p], b1 = (float)qr1[2 * p + 1];
        qr1[2 * p]     = (bf16)((b0 * c1.x - b1 * c1.y) * 0.125f);
        qr1[2 * p + 1] = (bf16)((b1 * c1.x + b0 * c1.y) * 0.125f);
      }
    }
    bf16x8 qf0 = *(bf16x8*)qr0;
    bf16x8 qf1 = *(bf16x8*)qr1;
    f32x4 s[34];                            // s[33] exists only as a never-taken select arm
    // QK^T with one-tile register prefetch (reads of tl+1 fly under MFMA of tl)
    bf16x8 kb0[2], kb1[2];
    kb0[0] = *(const bf16x8*)(&Ks[m16 * 72 + quad * 8]);
    kb1[0] = *(const bf16x8*)(&Ks[m16 * 72 + 32 + quad * 8]);
    #pragma unroll
    for (int tl = 0; tl < 33; tl++) {
      if (tl < ntl) {                       // wave-uniform guard
        if (tl + 1 < ntl) {
          kb0[(tl + 1) & 1] = *(const bf16x8*)(&Ks[((tl + 1) * 16 + m16) * 72 + quad * 8]);
          kb1[(tl + 1) & 1] = *(const bf16x8*)(&Ks[((tl + 1) * 16 + m16) * 72 + 32 + quad * 8]);
        }
        __builtin_amdgcn_sched_barrier(0);
        f32x4 acc = {0.f, 0.f, 0.f, 0.f};
        acc = __builtin_amdgcn_mfma_f32_16x16x32_bf16(qf0, kb0[tl & 1], acc, 0, 0, 0);
        acc = __builtin_amdgcn_mfma_f32_16x16x32_bf16(qf1, kb1[tl & 1], acc, 0, 0, 0);
        if (tl == qi + 1) {                 // diagonal tile: mask m16 > quad*4+r
          #pragma unroll
          for (int r = 0; r < 4; r++)
            if (m16 > quad * 4 + r) acc[r] = -1e30f;
        }
        s[tl] = acc;
      }
    }
    // softmax over visible tiles + 16 lanes of the column group
    float lrow[4];
    #pragma unroll
    for (int r = 0; r < 4; r++) {
      float mx = s[0][r];
      #pragma unroll
      for (int tl = 1; tl < 33; tl++) if (tl < ntl) mx = fmaxf(mx, s[tl][r]);
      mx = fmaxf(mx, __shfl_xor(mx, 1, 64));
      mx = fmaxf(mx, __shfl_xor(mx, 2, 64));
      mx = fmaxf(mx, __shfl_xor(mx, 4, 64));
      mx = fmaxf(mx, __shfl_xor(mx, 8, 64));
      float sum = 0.f;
      #pragma unroll
      for (int tl = 0; tl < 33; tl++) {
        if (tl < ntl) {
          float p = exp2f((s[tl][r] - mx) * LOG2E);
          s[tl][r] = p;
          sum += p;
        }
      }
      sum += __shfl_xor(sum, 1, 64);
      sum += __shfl_xor(sum, 2, 64);
      sum += __shfl_xor(sum, 4, 64);
      sum += __shfl_xor(sum, 8, 64);
      lrow[r] = sum;
    }
    // PV over visible chunks of 32 kv, pipelined one chunk ahead.
    // Same-wave DS ops execute in order: PWRITE(c+1) then PREAD(c+1) needs no drain,
    // and pf/vfr(c) were issued 13 DS ops ago -> MFMA(c) starts immediately.
    f32x4 o[4] = {};
    bf16x8 pf[2], vfr[2][4];

#define PWRITE(C) { \
      _Pragma("unroll") for (int half = 0; half < 2; half++) { \
        const int tl = 2 * (C) + half; \
        int pwo = half ? pw1 : pw0; \
        _Pragma("unroll") for (int r = 0; r < 4; r++) { \
          float pv = (tl < ntl) ? s[tl][r] : 0.f; \
          myP[(quad * 4 + r) * 40 + pwo] = (bf16)pv; } } }
#define PVLOAD(PAR, C) { \
      asm volatile("" ::: "memory"); \
      pf[PAR] = *(const bf16x8*)(&myP[prd]); \
      _Pragma("unroll") for (int dt = 0; dt < 4; dt++) \
        vfr[PAR][dt] = *(const bf16x8*)(&Vt[((C) < 16 ? vswz[dt] : vpl[dt]) + (C) * 32]); }

    PWRITE(0)
    PVLOAD(0, 0)
    #pragma unroll
    for (int c = 0; c < 17; c++) {
      if (2 * c < ntl) {                    // wave-uniform guard
        if (2 * (c + 1) < ntl) {            // prefetch chunk c+1
          PWRITE(c + 1)
          PVLOAD((c + 1) & 1, c + 1)
        }
        __builtin_amdgcn_sched_barrier(0);
        #pragma unroll
        for (int dt = 0; dt < 4; dt++)
          o[dt] = __builtin_amdgcn_mfma_f32_16x16x32_bf16(pf[c & 1], vfr[c & 1][dt], o[dt], 0, 0, 0);
      }
    }
#undef PVLOAD
#undef PWRITE
    // normalize + write to [8192][1024] merged layout
    float invl[4];
    #pragma unroll
    for (int r = 0; r < 4; r++) invl[r] = 1.0f / lrow[r];
    #pragma unroll
    for (int dt = 0; dt < 4; dt++)
      #pragma unroll
      for (int r = 0; r < 4; r++) {
        size_t row = (size_t)bw * 512 + q0 + quad * 4 + r;
        ob[row * 1024 + h * 64 + dt * 16 + m16] = (bf16)(o[dt][r] * invl[r]);
      }
  }
}

// ---------------- launch ----------------
extern "C" void kernel_launch(void* const* d_in, const int* in_sizes, int n_in,
                              void* d_out, int out_size, void* d_ws, size_t ws_size,
                              hipStream_t stream) {
  const float* seq  = (const float*)d_in[0];
  const float* g    = (const float*)d_in[1];
  const float* wqkv = (const float*)d_in[2];
  const float* wout = (const float*)d_in[3];
  const float* pm   = (const float*)d_in[4];
  float* out = (float*)d_out;
  char* ws = (char*)d_ws;
  bf16*   wqkv_bf = (bf16*)(ws);                  //  6,291,456
  bf16*   wout_bf = (bf16*)(ws + 6291456);        //  2,097,152
  bf16*   pm_bf   = (bf16*)(ws + 8388608);        //     65,536
  float2* tab     = (float2*)(ws + 8454144);      //  1,048,576 (4096 x 32 cos/sin)
  bf16*   x_bf    = (bf16*)(ws + 9502720);        // 16,777,216 (RMSNorm out, reused as attn out)
  bf16*   qkv_bf  = (bf16*)(ws + 26279936);       // 50,331,648 -> 76,611,584 total

  cast3_kernel<<<4640, 256, 0, stream>>>(wqkv, 786432, wqkv_bf,
                                         wout, 262144, wout_bf,
                                         pm, 8192, pm_bf,
                                         tab, 131072);
  rmsnorm_kernel<<<8192, 256, 0, stream>>>(seq, g, x_bf);
  gemm128x256_kernel<0><<<dim3(12, 64), 512, 0, stream>>>(x_bf, wqkv_bf, qkv_bf, 8192, 3072, 1024);
  attn_kernel<<<256, 512, 0, stream>>>(qkv_bf, pm_bf, tab, x_bf);
  gemm128x256_kernel<1><<<dim3(4, 64), 512, 0, stream>>>(x_bf, wout_bf, out, 8192, 1024, 1024);
}

// Round 7
// 223.863 us; speedup vs baseline: 1.0848x; 1.0634x over previous
//
#include <hip/hip_runtime.h>

typedef __bf16 bf16;
typedef __bf16 bf16x4 __attribute__((ext_vector_type(4)));
typedef __bf16 bf16x8 __attribute__((ext_vector_type(8)));
typedef float f32x4 __attribute__((ext_vector_type(4)));

#define LOG2E 1.44269504088896f

// async global->LDS, 16B per lane. LDS dest is wave-uniform base + lane*16
// (m104/m108): pass the lane-0 pointer; generic->AS(3) = low-32-bit truncation.
__device__ __forceinline__ void gl_lds16(const bf16* g, bf16* l) {
  __builtin_amdgcn_global_load_lds(
      reinterpret_cast<const __attribute__((address_space(1))) void*>((uintptr_t)g),
      reinterpret_cast<__attribute__((address_space(3))) void*>((uint32_t)(uintptr_t)l),
      16, 0, 0);
}

// ---------------- merged prep: RMSNorm (blocks 0..8191) + casts/RoPE table (rest) ----------------
__global__ __launch_bounds__(256) void prep_kernel(const float* __restrict__ seq,
                                                   const float* __restrict__ g,
                                                   bf16* __restrict__ xbf,
                                                   const float* __restrict__ a, int na4, bf16* __restrict__ oa,
                                                   const float* __restrict__ b, int nb4, bf16* __restrict__ ob,
                                                   const float* __restrict__ c, int nc4, bf16* __restrict__ oc,
                                                   float2* __restrict__ tab, int nt) {
  __shared__ float red[4];
  int bid = blockIdx.x;
  int t = threadIdx.x;
  if (bid < 8192) {                       // RMSNorm row
    int row = bid;
    float4 x = ((const float4*)(seq + (size_t)row * 1024))[t];
    float ss = x.x*x.x + x.y*x.y + x.z*x.z + x.w*x.w;
    #pragma unroll
    for (int m = 32; m >= 1; m >>= 1) ss += __shfl_xor(ss, m, 64);
    if ((t & 63) == 0) red[t >> 6] = ss;
    __syncthreads();
    float tot = red[0] + red[1] + red[2] + red[3];
    float scale = rsqrtf(tot * (1.0f / 1024.0f) + 1.1920929e-07f);
    float4 gv = ((const float4*)g)[t];
    bf16x4 o = { (bf16)(x.x*scale*gv.x), (bf16)(x.y*scale*gv.y),
                 (bf16)(x.z*scale*gv.z), (bf16)(x.w*scale*gv.w) };
    ((bf16x4*)(xbf + (size_t)row * 1024))[t] = o;
    return;
  }
  int i = (bid - 8192) * 256 + t;
  if (i < na4 + nb4 + nc4) {
    const float* src; bf16* dst; int idx;
    if (i < na4)            { src = a; dst = oa; idx = i; }
    else if (i < na4 + nb4) { src = b; dst = ob; idx = i - na4; }
    else                    { src = c; dst = oc; idx = i - na4 - nb4; }
    float4 v = ((const float4*)src)[idx];
    bf16x4 o = { (bf16)v.x, (bf16)v.y, (bf16)v.z, (bf16)v.w };
    ((bf16x4*)dst)[idx] = o;
  } else {
    int idx = i - (na4 + nb4 + nc4);
    if (idx >= nt) return;
    int pos = idx >> 5, fi = idx & 31;
    float inv = exp2f((float)fi * -0.41524101186f);   // 10000^(-fi/32)
    float th = (float)pos * inv;
    float sn, cs;
    sincosf(th, &sn, &cs);
    tab[idx] = make_float2(cs, sn);
  }
}

// ---------------- 128x256 8-wave BK=32 GEMM, 2 blocks/CU, C = A * B^T ----------------
// Round 7: the phase was measured to execute LDS-reads + MFMA SERIALLY per wave
// (r3/r6: 1512 cyc vs 768+620 floors) regardless of source-level pipelining, so get
// the overlap from TLP instead: BK=32, triple-buffered LDS = 72 KB -> 2 blocks/CU
// = 16 waves/CU (4/SIMD).  __launch_bounds__(512,4) caps VGPR at 128 (est. ~120).
// One phase per k32 tile: RD(8 b128) -> DMA3(tile u+2) -> 16 MFMA -> vmcnt(3) -> bar.
// vmcnt(3) at end of tile u drains tile u+1's 3 loads, leaves u+2's 3 in flight;
// buf (u+2)%3 was last read at tile u-1 (2 barriers before restage).  Tail: VM0 at
// tile nt-2.  BK=32 window swizzle: slot s of each 128B row-pair window w holds
// logical chunk s^(w&7) (row 2w+((s^(w&7))>>2), k-chunk (s^(w&7))&3) -> per 8-lane
// group all eight 16B slots distinct = conflict-free ds_read_b128; DMA writes linear.
// Requires nt = K/32 with (nt-2)%3 == 0, nt >= 5 (K=1024 -> nt=32).
template<int OUTF>
__global__ __launch_bounds__(512, 4) void gemm_bk32_kernel(const bf16* __restrict__ A,
                                                           const bf16* __restrict__ B,
                                                           void* __restrict__ C,
                                                           int M, int N, int K) {
  __shared__ bf16 As[3 * 4096];    // [buf][128 rows][32 k] window-swizzled (8 KB/buf)
  __shared__ bf16 Bs[3 * 8192];    // [buf][256 rows][32 k] (16 KB/buf)
  int t = threadIdx.x;
  int lane = t & 63, wv = t >> 6;
  int m16 = lane & 15, quad = lane >> 4;
  int wr = (wv >> 2) * 64, wc = (wv & 3) * 64;   // 2M x 4N waves, per-wave C = 64x64
  int bn = blockIdx.x, bm = blockIdx.y;
  const bf16* Ab = A + (size_t)bm * 128 * K;
  const bf16* Bb = B + (size_t)bn * 256 * K;
  // DMA pre-swizzled global source offsets (A: 512 chunks = 1/thread; B: 1024 = 2/thread)
  int aoff, boff1;
  { int i = t;       int w = i >> 3, so = (i & 7) ^ (w & 7); aoff  = (2*w + (so >> 2)) * K + (so & 3) * 8; }
  { int i = 512 + t; int w = i >> 3, so = (i & 7) ^ (w & 7); boff1 = (2*w + (so >> 2)) * K + (so & 3) * 8; }
  // read-side: element addr = window*64 + slot*8; slot = (((row&1)<<2)|quad) ^ ((row>>1)&7)
  int swzr = ((((m16 & 1) << 2) | quad) ^ (m16 >> 1));
  int abase = wr * 32 + (m16 >> 1) * 64 + swzr * 8;   // + i*512 per frag
  int bbase = wc * 32 + (m16 >> 1) * 64 + swzr * 8;   // + j*512 per frag
  f32x4 acc[4][4] = {};
  bf16x8 af[4], bq[4];

#define STG3(BUF, T) { int k0 = (T) * 32; \
    gl_lds16(Ab + k0 + aoff,  &As[(BUF) * 4096 + wv * 512]); \
    gl_lds16(Bb + k0 + aoff,  &Bs[(BUF) * 8192 + wv * 512]); \
    gl_lds16(Bb + k0 + boff1, &Bs[(BUF) * 8192 + 4096 + wv * 512]); }
#define VM3 asm volatile("s_waitcnt vmcnt(3)" ::: "memory");
#define VM0 asm volatile("s_waitcnt vmcnt(0)" ::: "memory");
#define BAR __builtin_amdgcn_s_barrier();
#define SB0 __builtin_amdgcn_sched_barrier(0);
#define PRIO1 __builtin_amdgcn_s_setprio(1);
#define PRIO0 __builtin_amdgcn_s_setprio(0);

#define RD(BUF) { \
    _Pragma("unroll") for (int i = 0; i < 4; i++) \
      af[i] = *(const bf16x8*)(&As[(BUF) * 4096 + abase + i * 512]); \
    _Pragma("unroll") for (int j = 0; j < 4; j++) \
      bq[j] = *(const bf16x8*)(&Bs[(BUF) * 8192 + bbase + j * 512]); }

#define MM { \
    _Pragma("unroll") for (int i = 0; i < 4; i++) { \
      _Pragma("unroll") for (int j = 0; j < 4; j++) { \
        acc[i][j] = __builtin_amdgcn_mfma_f32_16x16x32_bf16(af[i], bq[j], acc[i][j], 0, 0, 0); } } }

#define TILE(BUF, NBUF, T) { \
    RD(BUF) SB0 \
    STG3(NBUF, (T) + 2) SB0 \
    PRIO1 MM PRIO0 \
    VM3 BAR SB0 }

  // prologue: stage tiles 0,1; drain tile 0 (vmcnt(3) leaves tile 1's 3 in flight)
  STG3(0, 0) STG3(1, 1)
  VM3
  BAR SB0

  int nt = K >> 5;                 // (nt-2) % 3 == 0, nt >= 5  (K=1024 -> nt=32)
  for (int tk = 0; tk < nt - 2; tk += 3) {
    TILE(0, 2, tk)
    TILE(1, 0, tk + 1)
    TILE(2, 1, tk + 2)
  }
  // tile nt-2 (buf 0): no DMA; drain tile nt-1's loads before its reads
  RD(0) SB0
  PRIO1 MM PRIO0
  VM0 BAR SB0
  // tile nt-1 (buf 1): final tile
  RD(1) SB0
  PRIO1 MM PRIO0

#undef TILE
#undef MM
#undef RD
#undef PRIO1
#undef PRIO0
#undef SB0
#undef BAR
#undef VM0
#undef VM3
#undef STG3

  #pragma unroll
  for (int i = 0; i < 4; i++)
    #pragma unroll
    for (int j = 0; j < 4; j++)
      #pragma unroll
      for (int r = 0; r < 4; r++) {
        size_t row = (size_t)bm * 128 + wr + i * 16 + quad * 4 + r;
        size_t col = (size_t)bn * 256 + wc + j * 16 + m16;
        float v = acc[i][j][r];
        if (OUTF) ((float*)C)[row * N + col] = v;
        else      ((bf16*)C)[row * N + col] = (bf16)v;
      }
}

// ---------------- 128x256 8-wave BK=64 pipelined GEMM (r6, kept for out-proj) ----------------
// Triple-buffered LDS (144 KiB), DMA 2 tiles ahead, counted vmcnt(6)/tile, register
// double-buffer.  Requires nt = K/64, nt % 3 == 1, nt >= 7 (K=1024 -> nt=16).
template<int OUTF>
__global__ __launch_bounds__(512) void gemm128x256_kernel(const bf16* __restrict__ A,
                                                          const bf16* __restrict__ B,
                                                          void* __restrict__ C,
                                                          int M, int N, int K) {
  __shared__ bf16 As[3 * 8192];    // [buf][128 rows][64 k], XOR-swizzled chunks
  __shared__ bf16 Bs[3 * 16384];   // [buf][256 rows][64 k]
  int t = threadIdx.x;
  int lane = t & 63, wv = t >> 6;
  int m16 = lane & 15, quad = lane >> 4;
  int wr = (wv >> 2) * 64, wc = (wv & 3) * 64;   // 2M x 4N waves, per-wave C = 64x64
  int bn = blockIdx.x, bm = blockIdx.y;
  const bf16* Ab = A + (size_t)bm * 128 * K;
  const bf16* Bb = B + (size_t)bn * 256 * K;
  int aoff[2], boff[4];
  #pragma unroll
  for (int l = 0; l < 2; l++) { int s = l * 512 + t; int row = s >> 3; aoff[l] = row * K + ((s & 7) ^ (row & 7)) * 8; }
  #pragma unroll
  for (int l = 0; l < 4; l++) { int s = l * 512 + t; int row = s >> 3; boff[l] = row * K + ((s & 7) ^ (row & 7)) * 8; }
  int aadr[4], badr[4];
  #pragma unroll
  for (int i = 0; i < 4; i++) { int row = wr + i * 16 + m16; aadr[i] = row * 64 + ((quad ^ (row & 7)) * 8); }
  #pragma unroll
  for (int j = 0; j < 4; j++) { int row = wc + j * 16 + m16; badr[j] = row * 64 + ((quad ^ (row & 7)) * 8); }
  f32x4 acc[4][4] = {};
  bf16x8 afA[4], bqA[4], afB[4], bqB[4];

#define STGA(BUF, T) { int k0 = (T) * 64; \
    gl_lds16(Ab + k0 + aoff[0], &As[(BUF) * 8192 + wv * 512]); \
    gl_lds16(Ab + k0 + aoff[1], &As[(BUF) * 8192 + 4096 + wv * 512]); }
#define STGB(BUF, T, L) { int k0 = (T) * 64; \
    gl_lds16(Bb + k0 + boff[L], &Bs[(BUF) * 16384 + (L) * 4096 + wv * 512]); }
#define DMA6(BUF, T) { STGA(BUF, T) STGB(BUF, T, 0) STGB(BUF, T, 1) STGB(BUF, T, 2) STGB(BUF, T, 3) }
#define VM6 asm volatile("s_waitcnt vmcnt(6)" ::: "memory");
#define VM0 asm volatile("s_waitcnt vmcnt(0)" ::: "memory");
#define BAR __builtin_amdgcn_s_barrier();
#define SB0 __builtin_amdgcn_sched_barrier(0);
#define PRIO1 __builtin_amdgcn_s_setprio(1);
#define PRIO0 __builtin_amdgcn_s_setprio(0);

#define RD(AF, BQ, BUF, KX) { \
    _Pragma("unroll") for (int i = 0; i < 4; i++) \
      AF[i] = *(const bf16x8*)(&As[(BUF) * 8192 + (aadr[i] ^ (KX))]); \
    _Pragma("unroll") for (int j = 0; j < 4; j++) \
      BQ[j] = *(const bf16x8*)(&Bs[(BUF) * 16384 + (badr[j] ^ (KX))]); }

#define MM(AF, BQ) { \
    _Pragma("unroll") for (int i = 0; i < 4; i++) { \
      _Pragma("unroll") for (int j = 0; j < 4; j++) { \
        acc[i][j] = __builtin_amdgcn_mfma_f32_16x16x32_bf16(AF[i], BQ[j], acc[i][j], 0, 0, 0); } } }

#define TILE_STEADY(CUR, NXT, DMAB, T) { \
    RD(afB, bqB, CUR, 32) SB0 \
    DMA6(DMAB, (T) + 2) SB0 \
    PRIO1 MM(afA, bqA) PRIO0 \
    VM6 BAR SB0 \
    RD(afA, bqA, NXT, 0) SB0 \
    PRIO1 MM(afB, bqB) PRIO0 \
    BAR SB0 }

  DMA6(0, 0) DMA6(1, 1)
  VM6
  BAR SB0
  RD(afA, bqA, 0, 0) SB0

  int nt = K >> 6;                 // nt % 3 == 1, nt >= 7
  for (int tk = 0; tk < nt - 4; tk += 3) {
    TILE_STEADY(0, 1, 2, tk)
    TILE_STEADY(1, 2, 0, tk + 1)
    TILE_STEADY(2, 0, 1, tk + 2)
  }
  TILE_STEADY(0, 1, 2, nt - 4)
  TILE_STEADY(1, 2, 0, nt - 3)
  RD(afB, bqB, 2, 32) SB0
  PRIO1 MM(afA, bqA) PRIO0
  VM0 BAR SB0
  RD(afA, bqA, 0, 0) SB0
  PRIO1 MM(afB, bqB) PRIO0
  BAR SB0
  RD(afB, bqB, 0, 32) SB0
  PRIO1 MM(afA, bqA)
  MM(afB, bqB) PRIO0

#undef TILE_STEADY
#undef MM
#undef RD
#undef PRIO1
#undef PRIO0
#undef SB0
#undef BAR
#undef VM0
#undef VM6
#undef DMA6
#undef STGB
#undef STGA

  #pragma unroll
  for (int i = 0; i < 4; i++)
    #pragma unroll
    for (int j = 0; j < 4; j++)
      #pragma unroll
      for (int r = 0; r < 4; r++) {
        size_t row = (size_t)bm * 128 + wr + i * 16 + quad * 4 + r;
        size_t col = (size_t)bn * 256 + wc + j * 16 + m16;
        float v = acc[i][j][r];
        if (OUTF) ((float*)C)[row * N + col] = v;
        else      ((bf16*)C)[row * N + col] = (bf16)v;
      }
}

// ---------------- attention: one block per (bw,h), 8 waves; RoPE fused; causal skip ----------------
// PV loop software-pipelined one chunk ahead using same-wave DS in-order execution;
// P k-group XOR-swizzled by quad; V staging j XOR-swizzled by (d>>3)&3 for j<512;
// K tiles prefetched one ahead in QK^T.
__global__ __launch_bounds__(512) void attn_kernel(const bf16* __restrict__ qkv,
                                                   const bf16* __restrict__ pmbf,
                                                   const float2* __restrict__ tab,
                                                   bf16* __restrict__ ob) {
  __shared__ bf16 Ks[528 * 72];          // K rows (rope'd), padded stride 72
  __shared__ bf16 Vt[64 * 536 + 16];     // V transposed [d][j], stride 536, zero-padded tail
  __shared__ bf16 Pb[8 * 16 * 40];       // per-wave P staging, stride 40, quad-XOR swizzled
  int bh = blockIdx.x;
  int bw = bh >> 4, h = bh & 15;
  int seg = bw & 7;
  int t = threadIdx.x;
  int wv = t >> 6, lane = t & 63;
  int m16 = lane & 15, quad = lane >> 4;
  const bf16* qk_base = qkv + (size_t)bw * 512 * 3072 + h * 64;  // row s at +s*3072; K +1024; V +2048
  for (int ch = t; ch < 4224; ch += 512) {
    int row = ch >> 3, d0 = (ch & 7) * 8;
    bf16 tmp[8];
    if (row < 16) {
      *(uint4*)tmp = *(const uint4*)(pmbf + ((size_t)h * 16 + row) * 64 + d0);
    } else {
      int s = row - 16;
      *(uint4*)tmp = *(const uint4*)(qk_base + (size_t)s * 3072 + 1024 + d0);
      int pos = seg * 512 + s;
      const float2* tb = tab + pos * 32 + (d0 >> 1);
      #pragma unroll
      for (int p = 0; p < 4; p++) {
        float2 cs = tb[p];
        float x0 = (float)tmp[2 * p], x1 = (float)tmp[2 * p + 1];
        tmp[2 * p]     = (bf16)(x0 * cs.x - x1 * cs.y);
        tmp[2 * p + 1] = (bf16)(x1 * cs.x + x0 * cs.y);
      }
    }
    *(uint4*)(&Ks[row * 72 + d0]) = *(uint4*)tmp;
  }
  for (int ch = t; ch < 4224; ch += 512) {
    int row = ch >> 3, d0 = (ch & 7) * 8;
    bf16 tmp[8];
    if (row < 16) *(uint4*)tmp = *(const uint4*)(pmbf + ((size_t)(16 + h) * 16 + row) * 64 + d0);
    else          *(uint4*)tmp = *(const uint4*)(qk_base + (size_t)(row - 16) * 3072 + 2048 + d0);
    int rs = (row < 512) ? (row ^ ((ch & 3) << 3)) : row;   // g = ((d0+i)>>3)&3 = ch&3
    #pragma unroll
    for (int i = 0; i < 8; i++) Vt[(d0 + i) * 536 + rs] = tmp[i];
  }
  if (t < 512) { int r = t >> 3, cc = 528 + (t & 7); Vt[r * 536 + cc] = (bf16)0.f; }
  if (t < 16) Vt[64 * 536 + t] = (bf16)0.f;
  __syncthreads();

  bf16* myP = &Pb[wv * 16 * 40];
  int prd = m16 * 40 + (((quad ^ (m16 >> 2)) & 3) << 3);               // P read (k-group=quad)
  int pw0 = ((((m16 >> 3) ^ quad) & 3) << 3) | (m16 & 7);              // P write col, half 0
  int pw1 = ((((2 | (m16 >> 3)) ^ quad) & 3) << 3) | (m16 & 7);        // P write col, half 1
  int vswz[4], vpl[4];
  #pragma unroll
  for (int dt = 0; dt < 4; dt++) {
    int d = dt * 16 + m16;
    vswz[dt] = d * 536 + (((quad ^ (d >> 3)) & 3) << 3);               // j<512 swizzled
    vpl[dt]  = d * 536 + (quad << 3);                                  // chunk 16 plain
  }
  for (int pass = 0; pass < 4; pass++) {
    int qi = (pass == 0) ? wv : (pass == 1) ? 15 - wv : (pass == 2) ? 16 + wv : 31 - wv;
    int q0 = qi * 16;
    int ntl = qi + 2;                       // visible score tiles: 0..qi+1
    int qrow = q0 + m16;
    int pos = seg * 512 + qrow;
    const bf16* qp = qk_base + (size_t)qrow * 3072;
    bf16 qr0[8], qr1[8];
    *(uint4*)qr0 = *(const uint4*)(qp + quad * 8);
    *(uint4*)qr1 = *(const uint4*)(qp + 32 + quad * 8);
    {
      const float2* tb0 = tab + pos * 32 + quad * 4;
      const float2* tb1 = tb0 + 16;
      #pragma unroll
      for (int p = 0; p < 4; p++) {
        float2 c0 = tb0[p], c1 = tb1[p];
        float a0 = (float)qr0[2 * p], a1 = (float)qr0[2 * p + 1];
        qr0[2 * p]     = (bf16)((a0 * c0.x - a1 * c0.y) * 0.125f);
        qr0[2 * p + 1] = (bf16)((a1 * c0.x + a0 * c0.y) * 0.125f);
        float b0 = (float)qr1[2 * p], b1 = (float)qr1[2 * p + 1];
        qr1[2 * p]     = (bf16)((b0 * c1.x - b1 * c1.y) * 0.125f);
        qr1[2 * p + 1] = (bf16)((b1 * c1.x + b0 * c1.y) * 0.125f);
      }
    }
    bf16x8 qf0 = *(bf16x8*)qr0;
    bf16x8 qf1 = *(bf16x8*)qr1;
    f32x4 s[34];
    bf16x8 kb0[2], kb1[2];
    kb0[0] = *(const bf16x8*)(&Ks[m16 * 72 + quad * 8]);
    kb1[0] = *(const bf16x8*)(&Ks[m16 * 72 + 32 + quad * 8]);
    #pragma unroll
    for (int tl = 0; tl < 33; tl++) {
      if (tl < ntl) {                       // wave-uniform guard
        if (tl + 1 < ntl) {
          kb0[(tl + 1) & 1] = *(const bf16x8*)(&Ks[((tl + 1) * 16 + m16) * 72 + quad * 8]);
          kb1[(tl + 1) & 1] = *(const bf16x8*)(&Ks[((tl + 1) * 16 + m16) * 72 + 32 + quad * 8]);
        }
        __builtin_amdgcn_sched_barrier(0);
        f32x4 acc = {0.f, 0.f, 0.f, 0.f};
        acc = __builtin_amdgcn_mfma_f32_16x16x32_bf16(qf0, kb0[tl & 1], acc, 0, 0, 0);
        acc = __builtin_amdgcn_mfma_f32_16x16x32_bf16(qf1, kb1[tl & 1], acc, 0, 0, 0);
        if (tl == qi + 1) {                 // diagonal tile: mask m16 > quad*4+r
          #pragma unroll
          for (int r = 0; r < 4; r++)
            if (m16 > quad * 4 + r) acc[r] = -1e30f;
        }
        s[tl] = acc;
      }
    }
    float lrow[4];
    #pragma unroll
    for (int r = 0; r < 4; r++) {
      float mx = s[0][r];
      #pragma unroll
      for (int tl = 1; tl < 33; tl++) if (tl < ntl) mx = fmaxf(mx, s[tl][r]);
      mx = fmaxf(mx, __shfl_xor(mx, 1, 64));
      mx = fmaxf(mx, __shfl_xor(mx, 2, 64));
      mx = fmaxf(mx, __shfl_xor(mx, 4, 64));
      mx = fmaxf(mx, __shfl_xor(mx, 8, 64));
      float sum = 0.f;
      #pragma unroll
      for (int tl = 0; tl < 33; tl++) {
        if (tl < ntl) {
          float p = exp2f((s[tl][r] - mx) * LOG2E);
          s[tl][r] = p;
          sum += p;
        }
      }
      sum += __shfl_xor(sum, 1, 64);
      sum += __shfl_xor(sum, 2, 64);
      sum += __shfl_xor(sum, 4, 64);
      sum += __shfl_xor(sum, 8, 64);
      lrow[r] = sum;
    }
    f32x4 o[4] = {};
    bf16x8 pf[2], vfr[2][4];

#define PWRITE(C) { \
      _Pragma("unroll") for (int half = 0; half < 2; half++) { \
        const int tl = 2 * (C) + half; \
        int pwo = half ? pw1 : pw0; \
        _Pragma("unroll") for (int r = 0; r < 4; r++) { \
          float pv = (tl < ntl) ? s[tl][r] : 0.f; \
          myP[(quad * 4 + r) * 40 + pwo] = (bf16)pv; } } }
#define PVLOAD(PAR, C) { \
      asm volatile("" ::: "memory"); \
      pf[PAR] = *(const bf16x8*)(&myP[prd]); \
      _Pragma("unroll") for (int dt = 0; dt < 4; dt++) \
        vfr[PAR][dt] = *(const bf16x8*)(&Vt[((C) < 16 ? vswz[dt] : vpl[dt]) + (C) * 32]); }

    PWRITE(0)
    PVLOAD(0, 0)
    #pragma unroll
    for (int c = 0; c < 17; c++) {
      if (2 * c < ntl) {                    // wave-uniform guard
        if (2 * (c + 1) < ntl) {            // prefetch chunk c+1
          PWRITE(c + 1)
          PVLOAD((c + 1) & 1, c + 1)
        }
        __builtin_amdgcn_sched_barrier(0);
        #pragma unroll
        for (int dt = 0; dt < 4; dt++)
          o[dt] = __builtin_amdgcn_mfma_f32_16x16x32_bf16(pf[c & 1], vfr[c & 1][dt], o[dt], 0, 0, 0);
      }
    }
#undef PVLOAD
#undef PWRITE
    float invl[4];
    #pragma unroll
    for (int r = 0; r < 4; r++) invl[r] = 1.0f / lrow[r];
    #pragma unroll
    for (int dt = 0; dt < 4; dt++)
      #pragma unroll
      for (int r = 0; r < 4; r++) {
        size_t row = (size_t)bw * 512 + q0 + quad * 4 + r;
        ob[row * 1024 + h * 64 + dt * 16 + m16] = (bf16)(o[dt][r] * invl[r]);
      }
  }
}

// ---------------- launch ----------------
extern "C" void kernel_launch(void* const* d_in, const int* in_sizes, int n_in,
                              void* d_out, int out_size, void* d_ws, size_t ws_size,
                              hipStream_t stream) {
  const float* seq  = (const float*)d_in[0];
  const float* g    = (const float*)d_in[1];
  const float* wqkv = (const float*)d_in[2];
  const float* wout = (const float*)d_in[3];
  const float* pm   = (const float*)d_in[4];
  float* out = (float*)d_out;
  char* ws = (char*)d_ws;
  bf16*   wqkv_bf = (bf16*)(ws);                  //  6,291,456
  bf16*   wout_bf = (bf16*)(ws + 6291456);        //  2,097,152
  bf16*   pm_bf   = (bf16*)(ws + 8388608);        //     65,536
  float2* tab     = (float2*)(ws + 8454144);      //  1,048,576 (4096 x 32 cos/sin)
  bf16*   x_bf    = (bf16*)(ws + 9502720);        // 16,777,216 (RMSNorm out, reused as attn out)
  bf16*   qkv_bf  = (bf16*)(ws + 26279936);       // 50,331,648 -> 76,611,584 total

  prep_kernel<<<12832, 256, 0, stream>>>(seq, g, x_bf,
                                         wqkv, 786432, wqkv_bf,
                                         wout, 262144, wout_bf,
                                         pm, 8192, pm_bf,
                                         tab, 131072);
  gemm_bk32_kernel<0><<<dim3(12, 64), 512, 0, stream>>>(x_bf, wqkv_bf, qkv_bf, 8192, 3072, 1024);
  attn_kernel<<<256, 512, 0, stream>>>(qkv_bf, pm_bf, tab, x_bf);
  gemm128x256_kernel<1><<<dim3(4, 64), 512, 0, stream>>>(x_bf, wout_bf, out, 8192, 1024, 1024);
}

// Round 8
// 223.818 us; speedup vs baseline: 1.0850x; 1.0002x over previous
//
#include <hip/hip_runtime.h>

typedef __bf16 bf16;
typedef __bf16 bf16x4 __attribute__((ext_vector_type(4)));
typedef __bf16 bf16x8 __attribute__((ext_vector_type(8)));
typedef float f32x4 __attribute__((ext_vector_type(4)));

#define LOG2E 1.44269504088896f

// async global->LDS, 16B per lane. LDS dest is wave-uniform base + lane*16
// (m104/m108): pass the lane-0 pointer; generic->AS(3) = low-32-bit truncation.
__device__ __forceinline__ void gl_lds16(const bf16* g, bf16* l) {
  __builtin_amdgcn_global_load_lds(
      reinterpret_cast<const __attribute__((address_space(1))) void*>((uintptr_t)g),
      reinterpret_cast<__attribute__((address_space(3))) void*>((uint32_t)(uintptr_t)l),
      16, 0, 0);
}

// ---------------- merged prep: RMSNorm (blocks 0..8191) + casts/RoPE table (rest) ----------------
__global__ __launch_bounds__(256) void prep_kernel(const float* __restrict__ seq,
                                                   const float* __restrict__ g,
                                                   bf16* __restrict__ xbf,
                                                   const float* __restrict__ a, int na4, bf16* __restrict__ oa,
                                                   const float* __restrict__ b, int nb4, bf16* __restrict__ ob,
                                                   const float* __restrict__ c, int nc4, bf16* __restrict__ oc,
                                                   float2* __restrict__ tab, int nt) {
  __shared__ float red[4];
  int bid = blockIdx.x;
  int t = threadIdx.x;
  if (bid < 8192) {                       // RMSNorm row
    int row = bid;
    float4 x = ((const float4*)(seq + (size_t)row * 1024))[t];
    float ss = x.x*x.x + x.y*x.y + x.z*x.z + x.w*x.w;
    #pragma unroll
    for (int m = 32; m >= 1; m >>= 1) ss += __shfl_xor(ss, m, 64);
    if ((t & 63) == 0) red[t >> 6] = ss;
    __syncthreads();
    float tot = red[0] + red[1] + red[2] + red[3];
    float scale = rsqrtf(tot * (1.0f / 1024.0f) + 1.1920929e-07f);
    float4 gv = ((const float4*)g)[t];
    bf16x4 o = { (bf16)(x.x*scale*gv.x), (bf16)(x.y*scale*gv.y),
                 (bf16)(x.z*scale*gv.z), (bf16)(x.w*scale*gv.w) };
    ((bf16x4*)(xbf + (size_t)row * 1024))[t] = o;
    return;
  }
  int i = (bid - 8192) * 256 + t;
  if (i < na4 + nb4 + nc4) {
    const float* src; bf16* dst; int idx;
    if (i < na4)            { src = a; dst = oa; idx = i; }
    else if (i < na4 + nb4) { src = b; dst = ob; idx = i - na4; }
    else                    { src = c; dst = oc; idx = i - na4 - nb4; }
    float4 v = ((const float4*)src)[idx];
    bf16x4 o = { (bf16)v.x, (bf16)v.y, (bf16)v.z, (bf16)v.w };
    ((bf16x4*)dst)[idx] = o;
  } else {
    int idx = i - (na4 + nb4 + nc4);
    if (idx >= nt) return;
    int pos = idx >> 5, fi = idx & 31;
    float inv = exp2f((float)fi * -0.41524101186f);   // 10000^(-fi/32)
    float th = (float)pos * inv;
    float sn, cs;
    sincosf(th, &sn, &cs);
    tab[idx] = make_float2(cs, sn);
  }
}

// ---------------- 128x256 8-wave BK=32 GEMM, 2 blocks/CU, C = A * B^T ----------------
// BK=32, triple-buffered LDS = 72 KB -> 2 blocks/CU = 16 waves/CU (4/SIMD).
// One phase per k32 tile: RD(8 b128) -> DMA3(tile u+2) -> 16 MFMA -> vmcnt(3) -> bar.
// Window swizzle: slot s of each 128B row-pair window w holds logical chunk s^(w&7).
// Requires nt = K/32 with (nt-2)%3 == 0, nt >= 5 (K=1024 -> nt=32).
template<int OUTF>
__global__ __launch_bounds__(512, 4) void gemm_bk32_kernel(const bf16* __restrict__ A,
                                                           const bf16* __restrict__ B,
                                                           void* __restrict__ C,
                                                           int M, int N, int K) {
  __shared__ bf16 As[3 * 4096];    // [buf][128 rows][32 k] window-swizzled (8 KB/buf)
  __shared__ bf16 Bs[3 * 8192];    // [buf][256 rows][32 k] (16 KB/buf)
  int t = threadIdx.x;
  int lane = t & 63, wv = t >> 6;
  int m16 = lane & 15, quad = lane >> 4;
  int wr = (wv >> 2) * 64, wc = (wv & 3) * 64;   // 2M x 4N waves, per-wave C = 64x64
  int bn = blockIdx.x, bm = blockIdx.y;
  const bf16* Ab = A + (size_t)bm * 128 * K;
  const bf16* Bb = B + (size_t)bn * 256 * K;
  // DMA pre-swizzled global source offsets (A: 512 chunks = 1/thread; B: 1024 = 2/thread)
  int aoff, boff1;
  { int i = t;       int w = i >> 3, so = (i & 7) ^ (w & 7); aoff  = (2*w + (so >> 2)) * K + (so & 3) * 8; }
  { int i = 512 + t; int w = i >> 3, so = (i & 7) ^ (w & 7); boff1 = (2*w + (so >> 2)) * K + (so & 3) * 8; }
  // read-side: element addr = window*64 + slot*8; slot = (((row&1)<<2)|quad) ^ ((row>>1)&7)
  int swzr = ((((m16 & 1) << 2) | quad) ^ (m16 >> 1));
  int abase = wr * 32 + (m16 >> 1) * 64 + swzr * 8;   // + i*512 per frag
  int bbase = wc * 32 + (m16 >> 1) * 64 + swzr * 8;   // + j*512 per frag
  f32x4 acc[4][4] = {};
  bf16x8 af[4], bq[4];

#define STG3(BUF, T) { int k0 = (T) * 32; \
    gl_lds16(Ab + k0 + aoff,  &As[(BUF) * 4096 + wv * 512]); \
    gl_lds16(Bb + k0 + aoff,  &Bs[(BUF) * 8192 + wv * 512]); \
    gl_lds16(Bb + k0 + boff1, &Bs[(BUF) * 8192 + 4096 + wv * 512]); }
#define VM3 asm volatile("s_waitcnt vmcnt(3)" ::: "memory");
#define VM0 asm volatile("s_waitcnt vmcnt(0)" ::: "memory");
#define BAR __builtin_amdgcn_s_barrier();
#define SB0 __builtin_amdgcn_sched_barrier(0);
#define PRIO1 __builtin_amdgcn_s_setprio(1);
#define PRIO0 __builtin_amdgcn_s_setprio(0);

#define RD(BUF) { \
    _Pragma("unroll") for (int i = 0; i < 4; i++) \
      af[i] = *(const bf16x8*)(&As[(BUF) * 4096 + abase + i * 512]); \
    _Pragma("unroll") for (int j = 0; j < 4; j++) \
      bq[j] = *(const bf16x8*)(&Bs[(BUF) * 8192 + bbase + j * 512]); }

#define MM { \
    _Pragma("unroll") for (int i = 0; i < 4; i++) { \
      _Pragma("unroll") for (int j = 0; j < 4; j++) { \
        acc[i][j] = __builtin_amdgcn_mfma_f32_16x16x32_bf16(af[i], bq[j], acc[i][j], 0, 0, 0); } } }

#define TILE(BUF, NBUF, T) { \
    RD(BUF) SB0 \
    STG3(NBUF, (T) + 2) SB0 \
    PRIO1 MM PRIO0 \
    VM3 BAR SB0 }

  // prologue: stage tiles 0,1; drain tile 0 (vmcnt(3) leaves tile 1's 3 in flight)
  STG3(0, 0) STG3(1, 1)
  VM3
  BAR SB0

  int nt = K >> 5;                 // (nt-2) % 3 == 0, nt >= 5  (K=1024 -> nt=32)
  for (int tk = 0; tk < nt - 2; tk += 3) {
    TILE(0, 2, tk)
    TILE(1, 0, tk + 1)
    TILE(2, 1, tk + 2)
  }
  // tile nt-2 (buf 0): no DMA; drain tile nt-1's loads before its reads
  RD(0) SB0
  PRIO1 MM PRIO0
  VM0 BAR SB0
  // tile nt-1 (buf 1): final tile
  RD(1) SB0
  PRIO1 MM PRIO0

#undef TILE
#undef MM
#undef RD
#undef PRIO1
#undef PRIO0
#undef SB0
#undef BAR
#undef VM0
#undef VM3
#undef STG3

  #pragma unroll
  for (int i = 0; i < 4; i++)
    #pragma unroll
    for (int j = 0; j < 4; j++)
      #pragma unroll
      for (int r = 0; r < 4; r++) {
        size_t row = (size_t)bm * 128 + wr + i * 16 + quad * 4 + r;
        size_t col = (size_t)bn * 256 + wc + j * 16 + m16;
        float v = acc[i][j][r];
        if (OUTF) ((float*)C)[row * N + col] = v;
        else      ((bf16*)C)[row * N + col] = (bf16)v;
      }
}

// ---------------- 128x256 8-wave BK=64 pipelined GEMM (kept for out-proj) ----------------
// Triple-buffered LDS (144 KiB), DMA 2 tiles ahead, counted vmcnt(6)/tile, register
// double-buffer.  Requires nt = K/64, nt % 3 == 1, nt >= 7 (K=1024 -> nt=16).
template<int OUTF>
__global__ __launch_bounds__(512) void gemm128x256_kernel(const bf16* __restrict__ A,
                                                          const bf16* __restrict__ B,
                                                          void* __restrict__ C,
                                                          int M, int N, int K) {
  __shared__ bf16 As[3 * 8192];    // [buf][128 rows][64 k], XOR-swizzled chunks
  __shared__ bf16 Bs[3 * 16384];   // [buf][256 rows][64 k]
  int t = threadIdx.x;
  int lane = t & 63, wv = t >> 6;
  int m16 = lane & 15, quad = lane >> 4;
  int wr = (wv >> 2) * 64, wc = (wv & 3) * 64;   // 2M x 4N waves, per-wave C = 64x64
  int bn = blockIdx.x, bm = blockIdx.y;
  const bf16* Ab = A + (size_t)bm * 128 * K;
  const bf16* Bb = B + (size_t)bn * 256 * K;
  int aoff[2], boff[4];
  #pragma unroll
  for (int l = 0; l < 2; l++) { int s = l * 512 + t; int row = s >> 3; aoff[l] = row * K + ((s & 7) ^ (row & 7)) * 8; }
  #pragma unroll
  for (int l = 0; l < 4; l++) { int s = l * 512 + t; int row = s >> 3; boff[l] = row * K + ((s & 7) ^ (row & 7)) * 8; }
  int aadr[4], badr[4];
  #pragma unroll
  for (int i = 0; i < 4; i++) { int row = wr + i * 16 + m16; aadr[i] = row * 64 + ((quad ^ (row & 7)) * 8); }
  #pragma unroll
  for (int j = 0; j < 4; j++) { int row = wc + j * 16 + m16; badr[j] = row * 64 + ((quad ^ (row & 7)) * 8); }
  f32x4 acc[4][4] = {};
  bf16x8 afA[4], bqA[4], afB[4], bqB[4];

#define STGA(BUF, T) { int k0 = (T) * 64; \
    gl_lds16(Ab + k0 + aoff[0], &As[(BUF) * 8192 + wv * 512]); \
    gl_lds16(Ab + k0 + aoff[1], &As[(BUF) * 8192 + 4096 + wv * 512]); }
#define STGB(BUF, T, L) { int k0 = (T) * 64; \
    gl_lds16(Bb + k0 + boff[L], &Bs[(BUF) * 16384 + (L) * 4096 + wv * 512]); }
#define DMA6(BUF, T) { STGA(BUF, T) STGB(BUF, T, 0) STGB(BUF, T, 1) STGB(BUF, T, 2) STGB(BUF, T, 3) }
#define VM6 asm volatile("s_waitcnt vmcnt(6)" ::: "memory");
#define VM0 asm volatile("s_waitcnt vmcnt(0)" ::: "memory");
#define BAR __builtin_amdgcn_s_barrier();
#define SB0 __builtin_amdgcn_sched_barrier(0);
#define PRIO1 __builtin_amdgcn_s_setprio(1);
#define PRIO0 __builtin_amdgcn_s_setprio(0);

#define RD(AF, BQ, BUF, KX) { \
    _Pragma("unroll") for (int i = 0; i < 4; i++) \
      AF[i] = *(const bf16x8*)(&As[(BUF) * 8192 + (aadr[i] ^ (KX))]); \
    _Pragma("unroll") for (int j = 0; j < 4; j++) \
      BQ[j] = *(const bf16x8*)(&Bs[(BUF) * 16384 + (badr[j] ^ (KX))]); }

#define MM(AF, BQ) { \
    _Pragma("unroll") for (int i = 0; i < 4; i++) { \
      _Pragma("unroll") for (int j = 0; j < 4; j++) { \
        acc[i][j] = __builtin_amdgcn_mfma_f32_16x16x32_bf16(AF[i], BQ[j], acc[i][j], 0, 0, 0); } } }

#define TILE_STEADY(CUR, NXT, DMAB, T) { \
    RD(afB, bqB, CUR, 32) SB0 \
    DMA6(DMAB, (T) + 2) SB0 \
    PRIO1 MM(afA, bqA) PRIO0 \
    VM6 BAR SB0 \
    RD(afA, bqA, NXT, 0) SB0 \
    PRIO1 MM(afB, bqB) PRIO0 \
    BAR SB0 }

  DMA6(0, 0) DMA6(1, 1)
  VM6
  BAR SB0
  RD(afA, bqA, 0, 0) SB0

  int nt = K >> 6;                 // nt % 3 == 1, nt >= 7
  for (int tk = 0; tk < nt - 4; tk += 3) {
    TILE_STEADY(0, 1, 2, tk)
    TILE_STEADY(1, 2, 0, tk + 1)
    TILE_STEADY(2, 0, 1, tk + 2)
  }
  TILE_STEADY(0, 1, 2, nt - 4)
  TILE_STEADY(1, 2, 0, nt - 3)
  RD(afB, bqB, 2, 32) SB0
  PRIO1 MM(afA, bqA) PRIO0
  VM0 BAR SB0
  RD(afA, bqA, 0, 0) SB0
  PRIO1 MM(afB, bqB) PRIO0
  BAR SB0
  RD(afB, bqB, 0, 32) SB0
  PRIO1 MM(afA, bqA)
  MM(afB, bqB) PRIO0

#undef TILE_STEADY
#undef MM
#undef RD
#undef PRIO1
#undef PRIO0
#undef SB0
#undef BAR
#undef VM0
#undef VM6
#undef DMA6
#undef STGB
#undef STGA

  #pragma unroll
  for (int i = 0; i < 4; i++)
    #pragma unroll
    for (int j = 0; j < 4; j++)
      #pragma unroll
      for (int r = 0; r < 4; r++) {
        size_t row = (size_t)bm * 128 + wr + i * 16 + quad * 4 + r;
        size_t col = (size_t)bn * 256 + wc + j * 16 + m16;
        float v = acc[i][j][r];
        if (OUTF) ((float*)C)[row * N + col] = v;
        else      ((bf16*)C)[row * N + col] = (bf16)v;
      }
}

// ---------------- attention: one block per (bw,h), 8 waves; RoPE fused; causal skip ----------------
// Round 8: conflict-free LDS layouts.
//  Ks[528][64]: linear 128B rows, chunk-XOR swizzle slot = chunk ^ (row&7).  QK^T reads
//  (row=tl*16+m16, chunk=quad / 4|quad) spread 64 lanes -> exactly 8 lanes per 16B slot
//  = bandwidth floor (was stride-72 = 8-way conflict on every K read).  Reads become
//  base + tl*1024 (compile-time offsets).
//  Vt[64][576]: stride ≡ 0 mod 128B, col' = col ^ (g(d)<<3) with g(d)=(d>>3)^((d&1)<<2)
//  (bijective within each 64-col block).  Staging transpose writes: 8 distinct slots per
//  step; PV reads: 8 lanes/slot floor.  Per-lane hoisted bases vb[dt][c&1], read addr =
//  base + (c>>1)*64.  Chunk-16 ragged tail: zeros pre-placed at slots {g^2,g^3} (disjoint
//  from data slots {g,g^1}).
__global__ __launch_bounds__(512, 2) void attn_kernel(const bf16* __restrict__ qkv,
                                                      const bf16* __restrict__ pmbf,
                                                      const float2* __restrict__ tab,
                                                      bf16* __restrict__ ob) {
  __shared__ bf16 Ks[528 * 64];          // K rows, 128B rows, chunk-XOR swizzled
  __shared__ bf16 Vt[64 * 576];          // V^T rows, col-XOR swizzled, block 8 zero-padded
  __shared__ bf16 Pb[8 * 16 * 40];       // per-wave P staging, stride 40, quad-XOR swizzled
  int bh = blockIdx.x;
  int bw = bh >> 4, h = bh & 15;
  int seg = bw & 7;
  int t = threadIdx.x;
  int wv = t >> 6, lane = t & 63;
  int m16 = lane & 15, quad = lane >> 4;
  const bf16* qk_base = qkv + (size_t)bw * 512 * 3072 + h * 64;  // row s at +s*3072; K +1024; V +2048
  // stage K rows (pm rows 0..15 unroped, seq rows 16..527 roped at global pos)
  for (int ch = t; ch < 4224; ch += 512) {
    int row = ch >> 3, d0 = (ch & 7) * 8;
    bf16 tmp[8];
    if (row < 16) {
      *(uint4*)tmp = *(const uint4*)(pmbf + ((size_t)h * 16 + row) * 64 + d0);
    } else {
      int s = row - 16;
      *(uint4*)tmp = *(const uint4*)(qk_base + (size_t)s * 3072 + 1024 + d0);
      int pos = seg * 512 + s;
      const float2* tb = tab + pos * 32 + (d0 >> 1);
      #pragma unroll
      for (int p = 0; p < 4; p++) {
        float2 cs = tb[p];
        float x0 = (float)tmp[2 * p], x1 = (float)tmp[2 * p + 1];
        tmp[2 * p]     = (bf16)(x0 * cs.x - x1 * cs.y);
        tmp[2 * p + 1] = (bf16)(x1 * cs.x + x0 * cs.y);
      }
    }
    *(uint4*)(&Ks[row * 64 + (((ch & 7) ^ (row & 7)) << 3)]) = *(uint4*)tmp;
  }
  // stage V transposed (no rope): V^T[d][j] stored at Vt[d*576 + (j ^ (g(d)<<3))]
  for (int ch = t; ch < 4224; ch += 512) {
    int row = ch >> 3, d0 = (ch & 7) * 8;   // row = j position
    bf16 tmp[8];
    if (row < 16) *(uint4*)tmp = *(const uint4*)(pmbf + ((size_t)(16 + h) * 16 + row) * 64 + d0);
    else          *(uint4*)tmp = *(const uint4*)(qk_base + (size_t)(row - 16) * 3072 + 2048 + d0);
    #pragma unroll
    for (int i = 0; i < 8; i++) {
      int gw = (ch & 7) ^ ((i & 1) << 2);           // g(d0+i): (d>>3)=ch&7, (d&1)=i&1
      Vt[(d0 + i) * 576 + (row ^ (gw << 3))] = tmp[i];
    }
  }
  // zero the chunk-16 ragged-tail slots: per row d, 16B zeros at slots g^2 and g^3 of block 8
  if (t < 128) {
    int d = t >> 1;
    int gd = ((d >> 3) ^ ((d & 1) << 2)) & 7;
    int col = 512 + ((((2 | (t & 1)) ^ gd)) << 3);
    uint4 z = {0u, 0u, 0u, 0u};
    *(uint4*)(&Vt[d * 576 + col]) = z;
  }
  __syncthreads();

  bf16* myP = &Pb[wv * 16 * 40];
  // per-lane constant offsets
  int prd = m16 * 40 + (((quad ^ (m16 >> 2)) & 3) << 3);               // P read (k-group=quad)
  int pw0 = ((((m16 >> 3) ^ quad) & 3) << 3) | (m16 & 7);              // P write col, half 0
  int pw1 = ((((2 | (m16 >> 3)) ^ quad) & 3) << 3) | (m16 & 7);        // P write col, half 1
  int kb0_base = m16 * 64 + (((quad ^ (m16 & 7))) << 3);               // K frag d 0..31
  int kb1_base = m16 * 64 + ((((4 | quad) ^ (m16 & 7))) << 3);         // K frag d 32..63
  int vb[4][2];
  #pragma unroll
  for (int dt = 0; dt < 4; dt++) {
    int d = dt * 16 + m16;
    int gd = ((d >> 3) ^ ((d & 1) << 2)) & 7;
    int lo = (quad * 8) ^ ((gd & 3) << 3);
    vb[dt][0] = d * 576 + ((gd >> 2) << 5) + lo;          // even chunks
    vb[dt][1] = d * 576 + ((1 ^ (gd >> 2)) << 5) + lo;    // odd chunks
  }
  for (int pass = 0; pass < 4; pass++) {
    int qi = (pass == 0) ? wv : (pass == 1) ? 15 - wv : (pass == 2) ? 16 + wv : 31 - wv;
    int q0 = qi * 16;
    int ntl = qi + 2;                       // visible score tiles: 0..qi+1
    int qrow = q0 + m16;
    int pos = seg * 512 + qrow;
    const bf16* qp = qk_base + (size_t)qrow * 3072;
    // load Q frags + rope + 1/8 scale in registers
    bf16 qr0[8], qr1[8];
    *(uint4*)qr0 = *(const uint4*)(qp + quad * 8);
    *(uint4*)qr1 = *(const uint4*)(qp + 32 + quad * 8);
    {
      const float2* tb0 = tab + pos * 32 + quad * 4;
      const float2* tb1 = tb0 + 16;
      #pragma unroll
      for (int p = 0; p < 4; p++) {
        float2 c0 = tb0[p], c1 = tb1[p];
        float a0 = (float)qr0[2 * p], a1 = (float)qr0[2 * p + 1];
        qr0[2 * p]     = (bf16)((a0 * c0.x - a1 * c0.y) * 0.125f);
        qr0[2 * p + 1] = (bf16)((a1 * c0.x + a0 * c0.y) * 0.125f);
        float b0 = (float)qr1[2 * p], b1 = (float)qr1[2 * p + 1];
        qr1[2 * p]     = (bf16)((b0 * c1.x - b1 * c1.y) * 0.125f);
        qr1[2 * p + 1] = (bf16)((b1 * c1.x + b0 * c1.y) * 0.125f);
      }
    }
    bf16x8 qf0 = *(bf16x8*)qr0;
    bf16x8 qf1 = *(bf16x8*)qr1;
    f32x4 s[34];                            // s[33] exists only as a never-taken select arm
    // QK^T with one-tile register prefetch (reads of tl+1 fly under MFMA of tl)
    bf16x8 kb0[2], kb1[2];
    kb0[0] = *(const bf16x8*)(&Ks[kb0_base]);
    kb1[0] = *(const bf16x8*)(&Ks[kb1_base]);
    #pragma unroll
    for (int tl = 0; tl < 33; tl++) {
      if (tl < ntl) {                       // wave-uniform guard
        if (tl + 1 < ntl) {
          kb0[(tl + 1) & 1] = *(const bf16x8*)(&Ks[(tl + 1) * 1024 + kb0_base]);
          kb1[(tl + 1) & 1] = *(const bf16x8*)(&Ks[(tl + 1) * 1024 + kb1_base]);
        }
        __builtin_amdgcn_sched_barrier(0);
        f32x4 acc = {0.f, 0.f, 0.f, 0.f};
        acc = __builtin_amdgcn_mfma_f32_16x16x32_bf16(qf0, kb0[tl & 1], acc, 0, 0, 0);
        acc = __builtin_amdgcn_mfma_f32_16x16x32_bf16(qf1, kb1[tl & 1], acc, 0, 0, 0);
        if (tl == qi + 1) {                 // diagonal tile: mask m16 > quad*4+r
          #pragma unroll
          for (int r = 0; r < 4; r++)
            if (m16 > quad * 4 + r) acc[r] = -1e30f;
        }
        s[tl] = acc;
      }
    }
    // softmax over visible tiles + 16 lanes of the column group
    float lrow[4];
    #pragma unroll
    for (int r = 0; r < 4; r++) {
      float mx = s[0][r];
      #pragma unroll
      for (int tl = 1; tl < 33; tl++) if (tl < ntl) mx = fmaxf(mx, s[tl][r]);
      mx = fmaxf(mx, __shfl_xor(mx, 1, 64));
      mx = fmaxf(mx, __shfl_xor(mx, 2, 64));
      mx = fmaxf(mx, __shfl_xor(mx, 4, 64));
      mx = fmaxf(mx, __shfl_xor(mx, 8, 64));
      float sum = 0.f;
      #pragma unroll
      for (int tl = 0; tl < 33; tl++) {
        if (tl < ntl) {
          float p = exp2f((s[tl][r] - mx) * LOG2E);
          s[tl][r] = p;
          sum += p;
        }
      }
      sum += __shfl_xor(sum, 1, 64);
      sum += __shfl_xor(sum, 2, 64);
      sum += __shfl_xor(sum, 4, 64);
      sum += __shfl_xor(sum, 8, 64);
      lrow[r] = sum;
    }
    // PV over visible chunks of 32 kv, pipelined one chunk ahead.
    f32x4 o[4] = {};
    bf16x8 pf[2], vfr[2][4];

#define PWRITE(C) { \
      _Pragma("unroll") for (int half = 0; half < 2; half++) { \
        const int tl = 2 * (C) + half; \
        int pwo = half ? pw1 : pw0; \
        _Pragma("unroll") for (int r = 0; r < 4; r++) { \
          float pv = (tl < ntl) ? s[tl][r] : 0.f; \
          myP[(quad * 4 + r) * 40 + pwo] = (bf16)pv; } } }
#define PVLOAD(PAR, C) { \
      asm volatile("" ::: "memory"); \
      pf[PAR] = *(const bf16x8*)(&myP[prd]); \
      _Pragma("unroll") for (int dt = 0; dt < 4; dt++) \
        vfr[PAR][dt] = *(const bf16x8*)(&Vt[vb[dt][(C) & 1] + ((C) >> 1) * 64]); }

    PWRITE(0)
    PVLOAD(0, 0)
    #pragma unroll
    for (int c = 0; c < 17; c++) {
      if (2 * c < ntl) {                    // wave-uniform guard
        if (2 * (c + 1) < ntl) {            // prefetch chunk c+1
          PWRITE(c + 1)
          PVLOAD((c + 1) & 1, c + 1)
        }
        __builtin_amdgcn_sched_barrier(0);
        #pragma unroll
        for (int dt = 0; dt < 4; dt++)
          o[dt] = __builtin_amdgcn_mfma_f32_16x16x32_bf16(pf[c & 1], vfr[c & 1][dt], o[dt], 0, 0, 0);
      }
    }
#undef PVLOAD
#undef PWRITE
    // normalize + write to [8192][1024] merged layout
    float invl[4];
    #pragma unroll
    for (int r = 0; r < 4; r++) invl[r] = 1.0f / lrow[r];
    #pragma unroll
    for (int dt = 0; dt < 4; dt++)
      #pragma unroll
      for (int r = 0; r < 4; r++) {
        size_t row = (size_t)bw * 512 + q0 + quad * 4 + r;
        ob[row * 1024 + h * 64 + dt * 16 + m16] = (bf16)(o[dt][r] * invl[r]);
      }
  }
}

// ---------------- launch ----------------
extern "C" void kernel_launch(void* const* d_in, const int* in_sizes, int n_in,
                              void* d_out, int out_size, void* d_ws, size_t ws_size,
                              hipStream_t stream) {
  const float* seq  = (const float*)d_in[0];
  const float* g    = (const float*)d_in[1];
  const float* wqkv = (const float*)d_in[2];
  const float* wout = (const float*)d_in[3];
  const float* pm   = (const float*)d_in[4];
  float* out = (float*)d_out;
  char* ws = (char*)d_ws;
  bf16*   wqkv_bf = (bf16*)(ws);                  //  6,291,456
  bf16*   wout_bf = (bf16*)(ws + 6291456);        //  2,097,152
  bf16*   pm_bf   = (bf16*)(ws + 8388608);        //     65,536
  float2* tab     = (float2*)(ws + 8454144);      //  1,048,576 (4096 x 32 cos/sin)
  bf16*   x_bf    = (bf16*)(ws + 9502720);        // 16,777,216 (RMSNorm out, reused as attn out)
  bf16*   qkv_bf  = (bf16*)(ws + 26279936);       // 50,331,648 -> 76,611,584 total

  prep_kernel<<<12832, 256, 0, stream>>>(seq, g, x_bf,
                                         wqkv, 786432, wqkv_bf,
                                         wout, 262144, wout_bf,
                                         pm, 8192, pm_bf,
                                         tab, 131072);
  gemm_bk32_kernel<0><<<dim3(12, 64), 512, 0, stream>>>(x_bf, wqkv_bf, qkv_bf, 8192, 3072, 1024);
  attn_kernel<<<256, 512, 0, stream>>>(qkv_bf, pm_bf, tab, x_bf);
  gemm128x256_kernel<1><<<dim3(4, 64), 512, 0, stream>>>(x_bf, wout_bf, out, 8192, 1024, 1024);
}